// Round 20
// baseline (1917.746 us; speedup 1.0000x reference)
//
#include <hip/hip_runtime.h>
#include <hip/hip_bf16.h>
#include <cstdint>

#define B_    8
#define C_    3
#define H_    32
#define W_    32
#define HID   512
#define HEADS 8
#define FILT  2048
#define L_    6
#define BLEN  256
#define NPIX  256
#define S_    (H_*W_*C_)   /* 3072 */
#define MROWS (B_*S_)      /* 24576 */

typedef unsigned short u16;
typedef short bf16x8 __attribute__((ext_vector_type(8)));
typedef float f32x4  __attribute__((ext_vector_type(4)));

__device__ __forceinline__ float bf2f(u16 u) {
    union { unsigned int i; float f; } x; x.i = ((unsigned int)u) << 16; return x.f;
}
__device__ __forceinline__ u16 f2bf(float f) {
    __hip_bfloat16 h = __float2bfloat16(f);
    return *reinterpret_cast<u16*>(&h);
}

#define GLP(p) ((const __attribute__((address_space(1))) void*)(p))
#define LLP(p) ((__attribute__((address_space(3))) void*)(p))

// ---------------------------------------------------------------------------
// Embedding gather + shift + positional -> x16 (bf16 residual stream).
// ---------------------------------------------------------------------------
__global__ __launch_bounds__(256) void k_embed(const float* __restrict__ X,
                                               const float* __restrict__ emb,
                                               u16* __restrict__ xo16) {
    int r = blockIdx.x;              // b*S + s
    int b = r / S_, s = r - b * S_;
    int h = s / (W_ * C_);
    int j = s - h * (W_ * C_);
    int tid = threadIdx.x;
    int d0 = tid << 1;               // 0,2,..,510

    float e0 = 0.f, e1 = 0.f;
    if (s > 0) {
        int sp = s - 1;
        int hp = sp / (W_ * C_);
        int jp = sp - hp * (W_ * C_);
        int cp = jp % C_;
        int wp = jp / C_;
        float xv = X[(((size_t)b * C_ + cp) * H_ + hp) * W_ + wp];
        int iv = (int)(xv * 255.0f) + cp * NPIX;
        float2 ev = *(const float2*)(emb + (size_t)iv * HID + d0);
        e0 = ev.x * 22.627416997969522f;   // sqrt(512)
        e1 = ev.y * 22.627416997969522f;
    }
    float p01[2];
#pragma unroll
    for (int q = 0; q < 2; ++q) {
        int d = d0 + q;
        float invd = expf((float)(d & 127) * -0.07252236513366287f);
        p01[q] = (d < 128) ? sinf((float)h * invd)
               : (d < 256) ? cosf((float)h * invd)
               : (d < 384) ? sinf((float)j * invd)
                           : cosf((float)j * invd);
    }
    ushort2 o;
    o.x = f2bf(e0 + p01[0]);
    o.y = f2bf(e1 + p01[1]);
    *(ushort2*)(xo16 + (size_t)r * HID + d0) = o;
}

// ---------------------------------------------------------------------------
// 64x64 tile transpose+convert: out[N][K] (bf16) = in[K][N] (fp32).
// ---------------------------------------------------------------------------
__global__ __launch_bounds__(256) void k_trans_g(const float* __restrict__ in,
                                                 u16* __restrict__ out,
                                                 int N, int K,
                                                 size_t inStride, size_t outStride) {
    __shared__ u16 T[64][72];
    in  += (size_t)blockIdx.z * inStride;
    out += (size_t)blockIdx.z * outStride;
    int n0 = blockIdx.x * 64, k0 = blockIdx.y * 64;
    int t = threadIdx.x;
    int r4 = t >> 4;            // 0..15
    int c4 = (t & 15) << 2;     // 0..60
#pragma unroll
    for (int pass = 0; pass < 4; ++pass) {
        int kr = pass * 16 + r4;
        float4 v = *(const float4*)(in + (size_t)(k0 + kr) * N + n0 + c4);
        T[c4 + 0][kr] = f2bf(v.x);
        T[c4 + 1][kr] = f2bf(v.y);
        T[c4 + 2][kr] = f2bf(v.z);
        T[c4 + 3][kr] = f2bf(v.w);
    }
    __syncthreads();
#pragma unroll
    for (int pass = 0; pass < 4; ++pass) {
        int n = pass * 16 + r4;
        ushort4 s = {T[n][c4], T[n][c4 + 1], T[n][c4 + 2], T[n][c4 + 3]};
        *(ushort4*)(out + (size_t)(n0 + n) * K + k0 + c4) = s;
    }
}

// ---------------------------------------------------------------------------
// Pure-bf16 MFMA GEMM, 128x128 tile, 4 waves, BK=64, DOUBLE-BUFFERED LDS
// (T3-minimum 2-phase): prologue stage buf0; per step {issue stage(t+1)
// into buf^1 -> compute from buf -> barrier -> flip}. The compiler's
// vmcnt(0)-before-barrier lands AFTER compute, so staging latency hides.
// C = A(M,K) @ Bt(N,K)^T [+bias][relu]. KT: compile-time K.
// XCD-aware 1D grid swizzle (nwg%8==0 at all call sites).
// ---------------------------------------------------------------------------
template<int QKV, int C_BF, int BIAS, int RELU, int PERM, int KT>
__global__ __launch_bounds__(256) void g_bf16(const u16* __restrict__ A,
                                              const u16* __restrict__ Bt,
                                              const float* __restrict__ bias,
                                              void* __restrict__ C0,
                                              void* __restrict__ C1,
                                              void* __restrict__ C2,
                                              int Nc, int nx) {
    __shared__ __align__(16) u16 smem[32768];   // 2 x (As 8192 | Bs 8192) u16
    int tid  = threadIdx.x;
    int lane = tid & 63;
    int w    = tid >> 6;                 // 0..3

    int qg  = (int)gridDim.x >> 3;
    int wg  = (blockIdx.x & 7) * qg + (blockIdx.x >> 3);
    int bx  = wg % nx, by = wg / nx;
    int row0 = by * 128, col0 = bx * 128;

    int l8 = lane >> 3;                  // 0..7
    int l7 = lane & 7;                   // 0..7
    int scol = (l7 ^ l8) << 3;           // pre-swizzled source col (elems)
    const u16* aP = A  + (size_t)(row0 + w * 32 + l8) * KT + scol;
    const u16* bP = Bt + (size_t)(col0 + w * 32 + l8) * KT + scol;

    int wr = (w >> 1) << 6;
    int wc = (w & 1) << 6;
    int lr = lane & 15;
    int kb = lane >> 4;

    f32x4 acc[4][4];
#pragma unroll
    for (int mi = 0; mi < 4; ++mi)
#pragma unroll
        for (int nj = 0; nj < 4; ++nj)
            acc[mi][nj] = (f32x4){0.f, 0.f, 0.f, 0.f};

    const int NT = KT / 64;

    // ---- prologue: stage tile 0 into buffer 0 ----
    {
        u16* as0 = smem + w * 2048;
        u16* bs0 = smem + 8192 + w * 2048;
#pragma unroll
        for (int p = 0; p < 4; ++p) {
            __builtin_amdgcn_global_load_lds(GLP(aP + (size_t)p * 8 * KT),
                                             LLP(as0 + p * 512), 16, 0, 0);
            __builtin_amdgcn_global_load_lds(GLP(bP + (size_t)p * 8 * KT),
                                             LLP(bs0 + p * 512), 16, 0, 0);
        }
        aP += 64; bP += 64;
    }
    __syncthreads();

    int buf = 0;
    for (int t = 0; t < NT; ++t) {
        // ---- issue next tile's staging into the other buffer ----
        if (t + 1 < NT) {
            u16* asN = smem + (buf ^ 1) * 16384 + w * 2048;
            u16* bsN = smem + (buf ^ 1) * 16384 + 8192 + w * 2048;
#pragma unroll
            for (int p = 0; p < 4; ++p) {
                __builtin_amdgcn_global_load_lds(GLP(aP + (size_t)p * 8 * KT),
                                                 LLP(asN + p * 512), 16, 0, 0);
                __builtin_amdgcn_global_load_lds(GLP(bP + (size_t)p * 8 * KT),
                                                 LLP(bsN + p * 512), 16, 0, 0);
            }
            aP += 64; bP += 64;
        }
        // ---- compute current buffer ----
        const u16* As = smem + buf * 16384;
        const u16* Bs = smem + buf * 16384 + 8192;
#pragma unroll
        for (int kh = 0; kh < 2; ++kh) {
            int sl = ((kh << 2) + kb) ^ (lr & 7);
            bf16x8 af[4], bv[4];
#pragma unroll
            for (int mi = 0; mi < 4; ++mi)
                af[mi] = *(const bf16x8*)&As[(wr + lr) * 64 + mi * 1024 + sl * 8];
#pragma unroll
            for (int nj = 0; nj < 4; ++nj)
                bv[nj] = *(const bf16x8*)&Bs[(wc + lr) * 64 + nj * 1024 + sl * 8];
            __builtin_amdgcn_s_setprio(1);
#pragma unroll
            for (int mi = 0; mi < 4; ++mi)
#pragma unroll
                for (int nj = 0; nj < 4; ++nj)
                    acc[mi][nj] = __builtin_amdgcn_mfma_f32_16x16x32_bf16(
                        af[mi], bv[nj], acc[mi][nj], 0, 0, 0);
            __builtin_amdgcn_s_setprio(0);
        }
        __syncthreads();       // drains this step's prefetch too (post-compute)
        buf ^= 1;
    }

    if (C_BF) {
        // ---- vectorized epilogue via smem (stride 136) ----
#pragma unroll
        for (int nj = 0; nj < 4; ++nj) {
            int colL = wc + (nj << 4) + lr;
            float bsv = BIAS ? bias[col0 + colL] : 0.f;
#pragma unroll
            for (int mi = 0; mi < 4; ++mi)
#pragma unroll
                for (int reg = 0; reg < 4; ++reg) {
                    int rowL = wr + (mi << 4) + (kb << 2) + reg;
                    float v = acc[mi][nj][reg] + bsv;
                    if (RELU) v = fmaxf(v, 0.f);
                    smem[rowL * 136 + colL] = f2bf(v);
                }
        }
        __syncthreads();
        u16* Cp; int cbase;
        if (QKV) {
            int sel = col0 >> 9;
            Cp = (u16*)(sel == 0 ? C0 : sel == 1 ? C1 : C2);
            cbase = col0 & 511;
        } else { Cp = (u16*)C0; cbase = col0; }
#pragma unroll
        for (int it = 0; it < 8; ++it) {
            int job  = tid + (it << 8);
            int rowL = job >> 4;
            int colL = (job & 15) << 3;
            bf16x8 vv = *(const bf16x8*)&smem[rowL * 136 + colL];
            *(bf16x8*)(Cp + (size_t)(row0 + rowL) * Nc + cbase + colL) = vv;
        }
    } else {
#pragma unroll
        for (int nj = 0; nj < 4; ++nj) {
            int colg = col0 + wc + (nj << 4) + lr;
            float bsv = BIAS ? bias[colg] : 0.f;
#pragma unroll
            for (int mi = 0; mi < 4; ++mi)
#pragma unroll
                for (int reg = 0; reg < 4; ++reg) {
                    int row = row0 + wr + (mi << 4) + (kb << 2) + reg;
                    float v = acc[mi][nj][reg] + bsv;
                    if (RELU) v = fmaxf(v, 0.f);
                    if (PERM) {
                        int bb = row / S_;
                        int ss = row - bb * S_;
                        int hh = ss / (W_ * C_);
                        int jj = ss - hh * (W_ * C_);
                        int ww = jj / C_;
                        int cc = jj - ww * C_;
                        ((float*)C0)[((((size_t)bb * C_ + cc) * H_ + hh) * W_ + ww)
                                     * NPIX + colg] = v;
                    } else {
                        ((float*)C0)[(size_t)row * Nc + colg] = v;
                    }
                }
        }
    }
}

// ---------------------------------------------------------------------------
// LEGACY fp32-staged MFMA GEMM — fallback path only.
// ---------------------------------------------------------------------------
template<int A_BF, int C_BF, int BIAS, int RELU>
__global__ __launch_bounds__(256) void g_mfma(const void* __restrict__ Ap,
                                              const float* __restrict__ Bw,
                                              const float* __restrict__ bias,
                                              void* __restrict__ Cp,
                                              int N, int K) {
    __shared__ __align__(16) u16 As[128][40];
    __shared__ __align__(16) u16 Bs[128][40];
    int tid  = threadIdx.x;
    int row0 = blockIdx.y * 128, col0 = blockIdx.x * 128;

    int ar  = tid >> 1;
    int akq = (tid & 1) << 4;
    int bkk = tid >> 5;
    int bnn = (tid & 31) << 2;

    int lane = tid & 63;
    int wv   = tid >> 6;
    int wr   = (wv >> 1) << 6;
    int wc   = (wv & 1) << 6;
    int lr   = lane & 15;
    int kb   = lane >> 4;

    f32x4 acc[4][4];
#pragma unroll
    for (int mi = 0; mi < 4; ++mi)
#pragma unroll
        for (int nj = 0; nj < 4; ++nj)
            acc[mi][nj] = (f32x4){0.f, 0.f, 0.f, 0.f};

    for (int k0 = 0; k0 < K; k0 += 32) {
        if (A_BF) {
            const u16* ap = (const u16*)Ap + (size_t)(row0 + ar) * K + k0 + akq;
#pragma unroll
            for (int p = 0; p < 4; ++p)
                *(ushort4*)&As[ar][akq + (p << 2)] = *(const ushort4*)(ap + (p << 2));
        } else {
            const float* ap = (const float*)Ap + (size_t)(row0 + ar) * K + k0 + akq;
#pragma unroll
            for (int p = 0; p < 4; ++p) {
                float4 v = *(const float4*)(ap + (p << 2));
                ushort4 wq = {f2bf(v.x), f2bf(v.y), f2bf(v.z), f2bf(v.w)};
                *(ushort4*)&As[ar][akq + (p << 2)] = wq;
            }
        }
#pragma unroll
        for (int p = 0; p < 4; ++p) {
            int kl = bkk + (p << 3);
            float4 wv4 = *(const float4*)(Bw + (size_t)(k0 + kl) * N + col0 + bnn);
            Bs[bnn + 0][kl] = f2bf(wv4.x);
            Bs[bnn + 1][kl] = f2bf(wv4.y);
            Bs[bnn + 2][kl] = f2bf(wv4.z);
            Bs[bnn + 3][kl] = f2bf(wv4.w);
        }
        __syncthreads();

        bf16x8 af[4], bfr[4];
#pragma unroll
        for (int mi = 0; mi < 4; ++mi)
            af[mi] = *(const bf16x8*)&As[wr + (mi << 4) + lr][kb << 3];
#pragma unroll
        for (int nj = 0; nj < 4; ++nj)
            bfr[nj] = *(const bf16x8*)&Bs[wc + (nj << 4) + lr][kb << 3];
#pragma unroll
        for (int mi = 0; mi < 4; ++mi)
#pragma unroll
            for (int nj = 0; nj < 4; ++nj)
                acc[mi][nj] = __builtin_amdgcn_mfma_f32_16x16x32_bf16(
                    af[mi], bfr[nj], acc[mi][nj], 0, 0, 0);
        __syncthreads();
    }

#pragma unroll
    for (int mi = 0; mi < 4; ++mi)
#pragma unroll
        for (int nj = 0; nj < 4; ++nj) {
            int col = col0 + wc + (nj << 4) + lr;
            float bsv = BIAS ? bias[col] : 0.f;
#pragma unroll
            for (int reg = 0; reg < 4; ++reg) {
                int row = row0 + wr + (mi << 4) + (kb << 2) + reg;
                float v = acc[mi][nj][reg] + bsv;
                if (RELU) v = fmaxf(v, 0.f);
                if (C_BF)
                    ((u16*)Cp)[(size_t)row * N + col] = f2bf(v);
                else
                    ((float*)Cp)[(size_t)row * N + col] = v;
            }
        }
}

// ---------------------------------------------------------------------------
// MFMA flash-style block-local causal attention (bf16), SWAPPED QK^T,
// XCD-aware 1D grid + K/V register prefetch.  (unchanged from round 19)
// ---------------------------------------------------------------------------
__global__ __launch_bounds__(256) void k_attn_mfma(const u16* Qm,
                                                   const u16* __restrict__ Km,
                                                   const u16* __restrict__ Vm,
                                                   u16* Om) {
    __shared__ __align__(16) u16 Kl[64][72];      // [key][d]
    __shared__ __align__(16) u16 VT[64][72];      // [d][key^vsw]
    __shared__ __align__(16) u16 Pl[4][64][64];   // per-wave [q][k^((q&7)<<3)]

    int f   = blockIdx.x;            // 0..767
    int xcd = f & 7;
    int t2  = f >> 3;
    int qb  = t2 % 12;
    int grp = t2 / 12;               // 0..7
    int bh  = (grp << 3) | xcd;
    int b   = bh >> 3, h = bh & 7;

    int tid = threadIdx.x;
    int lane = tid & 63;
    int w    = tid >> 6;
    int lr   = lane & 15;
    int kb   = lane >> 4;            // 0..3
    int qw   = qb * BLEN + w * 64;   // wave query base
    int vsw  = (tid & 7) << 3;       // VT write swizzle
    int psw  = (lr & 7) << 3;        // Pl swizzle for this lane's rows (q&7)

    bf16x8 qf[4][2];
#pragma unroll
    for (int mi = 0; mi < 4; ++mi)
#pragma unroll
        for (int ks = 0; ks < 2; ++ks)
            qf[mi][ks] = *(const bf16x8*)(Qm +
                ((size_t)b * S_ + qw + mi * 16 + lr) * HID + h * 64 + ks * 32 + kb * 8);

    f32x4 oacc[4][4];                 // [mi][dj]
    float lacc[4];
#pragma unroll
    for (int mi = 0; mi < 4; ++mi) {
        lacc[mi] = 0.f;
#pragma unroll
        for (int dj = 0; dj < 4; ++dj)
            oacc[mi][dj] = (f32x4){0.f, 0.f, 0.f, 0.f};
    }

    int kstart = (qb == 0) ? 0 : (qb - 1) * BLEN;
    int nch    = (qb == 0) ? 4 : 8;

    int key0 = tid >> 3;
    int key1 = (tid + 256) >> 3;
    int d8   = (tid & 7) << 3;

    bf16x8 kvr0, kvr1, vvr0, vvr1;
    {
        size_t g0 = ((size_t)b * S_ + kstart + key0) * HID + h * 64 + d8;
        size_t g1 = ((size_t)b * S_ + kstart + key1) * HID + h * 64 + d8;
        kvr0 = *(const bf16x8*)(Km + g0);
        vvr0 = *(const bf16x8*)(Vm + g0);
        kvr1 = *(const bf16x8*)(Km + g1);
        vvr1 = *(const bf16x8*)(Vm + g1);
    }

    for (int ck = 0; ck < nch; ++ck) {
        int ka = kstart + ck * 64;
        __syncthreads();
        *(bf16x8*)&Kl[key0][d8] = kvr0;
        *(bf16x8*)&Kl[key1][d8] = kvr1;
        {
            const u16* vu0 = (const u16*)&vvr0;
            const u16* vu1 = (const u16*)&vvr1;
            int kc0 = key0 ^ vsw, kc1 = key1 ^ vsw;
#pragma unroll
            for (int e = 0; e < 8; ++e) VT[d8 + e][kc0] = vu0[e];
#pragma unroll
            for (int e = 0; e < 8; ++e) VT[d8 + e][kc1] = vu1[e];
        }
        __syncthreads();

        if (ck + 1 < nch) {
            int kan = ka + 64;
            size_t g0 = ((size_t)b * S_ + kan + key0) * HID + h * 64 + d8;
            size_t g1 = ((size_t)b * S_ + kan + key1) * HID + h * 64 + d8;
            kvr0 = *(const bf16x8*)(Km + g0);
            vvr0 = *(const bf16x8*)(Vm + g0);
            kvr1 = *(const bf16x8*)(Km + g1);
            vvr1 = *(const bf16x8*)(Vm + g1);
        }

        if (ka <= qw + 63) {
            f32x4 sa[4][4];
#pragma unroll
            for (int nj = 0; nj < 4; ++nj)
#pragma unroll
                for (int mi = 0; mi < 4; ++mi)
                    sa[nj][mi] = (f32x4){0.f, 0.f, 0.f, 0.f};
#pragma unroll
            for (int ks = 0; ks < 2; ++ks) {
                bf16x8 kf[4];
#pragma unroll
                for (int nj = 0; nj < 4; ++nj)
                    kf[nj] = *(const bf16x8*)&Kl[nj * 16 + lr][ks * 32 + kb * 8];
                __builtin_amdgcn_s_setprio(1);
#pragma unroll
                for (int nj = 0; nj < 4; ++nj)
#pragma unroll
                    for (int mi = 0; mi < 4; ++mi)
                        sa[nj][mi] = __builtin_amdgcn_mfma_f32_16x16x32_bf16(
                            kf[nj], qf[mi][ks], sa[nj][mi], 0, 0, 0);
                __builtin_amdgcn_s_setprio(0);
            }
            bool diag = (ka + 63 > qw);
#pragma unroll
            for (int mi = 0; mi < 4; ++mi) {
                int qg2 = qw + mi * 16 + lr;
                float tsum = 0.f;
#pragma unroll
                for (int nj = 0; nj < 4; ++nj) {
                    ushort4 pk;
                    u16* pp = (u16*)&pk;
#pragma unroll
                    for (int reg = 0; reg < 4; ++reg) {
                        float s = sa[nj][mi][reg] * 0.125f;
                        float p = __expf(s);
                        if (diag && (ka + nj * 16 + kb * 4 + reg > qg2)) p = 0.f;
                        tsum += p;
                        pp[reg] = f2bf(p);
                    }
                    *(ushort4*)&Pl[w][mi * 16 + lr][(nj * 16 + kb * 4) ^ psw] = pk;
                }
                tsum += __shfl_xor(tsum, 16);
                tsum += __shfl_xor(tsum, 32);
                lacc[mi] += tsum;
            }
#pragma unroll
            for (int ks = 0; ks < 2; ++ks) {
                bf16x8 pf[4], vf[4];
#pragma unroll
                for (int mi = 0; mi < 4; ++mi)
                    pf[mi] = *(const bf16x8*)&Pl[w][mi * 16 + lr]
                                                 [(ks * 32 + kb * 8) ^ psw];
#pragma unroll
                for (int dj = 0; dj < 4; ++dj) {
                    int vr = ((dj * 2 + (lr >> 3)) & 7) << 3;
                    vf[dj] = *(const bf16x8*)&VT[dj * 16 + lr]
                                                [(ks * 32 + kb * 8) ^ vr];
                }
                __builtin_amdgcn_s_setprio(1);
#pragma unroll
                for (int mi = 0; mi < 4; ++mi)
#pragma unroll
                    for (int dj = 0; dj < 4; ++dj)
                        oacc[mi][dj] = __builtin_amdgcn_mfma_f32_16x16x32_bf16(
                            pf[mi], vf[dj], oacc[mi][dj], 0, 0, 0);
                __builtin_amdgcn_s_setprio(0);
            }
        }
    }

#pragma unroll
    for (int mi = 0; mi < 4; ++mi) {
        float lr4[4];
#pragma unroll
        for (int reg = 0; reg < 4; ++reg)
            lr4[reg] = __shfl(lacc[mi], kb * 4 + reg);
#pragma unroll
        for (int reg = 0; reg < 4; ++reg) {
            float rl = 1.0f / lr4[reg];
            size_t orow = ((size_t)b * S_ + qw + mi * 16 + kb * 4 + reg) * HID + h * 64;
#pragma unroll
            for (int dj = 0; dj < 4; ++dj)
                Om[orow + dj * 16 + lr] = f2bf(oacc[mi][dj][reg] * rl);
        }
    }
}

// ---------------------------------------------------------------------------
// LEGACY scalar attention — fallback path only.
// ---------------------------------------------------------------------------
__global__ __launch_bounds__(256) void k_attn(const u16* Qm,
                                              const u16* __restrict__ Km,
                                              const u16* __restrict__ Vm,
                                              u16* Om) {
    __shared__ float Ks[64][64];
    __shared__ float Vs[64][64];
    int qb  = blockIdx.x;
    int bh  = blockIdx.y;
    int b   = bh >> 3, h = bh & 7;
    int tid = threadIdx.x;
    int sq  = qb * BLEN + tid;

    size_t qoff = ((size_t)b * S_ + sq) * HID + h * 64;
    float q[64];
#pragma unroll
    for (int d = 0; d < 64; d += 4) {
        ushort4 u = *(const ushort4*)(Qm + qoff + d);
        q[d]   = bf2f(u.x) * 0.125f;
        q[d+1] = bf2f(u.y) * 0.125f;
        q[d+2] = bf2f(u.z) * 0.125f;
        q[d+3] = bf2f(u.w) * 0.125f;
    }

    float acc[64];
#pragma unroll
    for (int d = 0; d < 64; ++d) acc[d] = 0.f;
    float l = 0.f;

    int kstart  = (qb == 0) ? 0 : (qb - 1) * BLEN;
    int nchunks = (qb == 0) ? 4 : 8;

    for (int ck = 0; ck < nchunks; ++ck) {
        int ka = kstart + ck * 64;
        __syncthreads();
        int li = tid;
#pragma unroll
        for (int it = 0; it < 4; ++it, li += 256) {
            int key = li >> 4;
            int seg = (li & 15) * 4;
            size_t goff = ((size_t)b * S_ + ka + key) * HID + h * 64 + seg;
            ushort4 ku = *(const ushort4*)(Km + goff);
            ushort4 vu = *(const ushort4*)(Vm + goff);
            Ks[key][seg+0] = bf2f(ku.x); Ks[key][seg+1] = bf2f(ku.y);
            Ks[key][seg+2] = bf2f(ku.z); Ks[key][seg+3] = bf2f(ku.w);
            Vs[key][seg+0] = bf2f(vu.x); Vs[key][seg+1] = bf2f(vu.y);
            Vs[key][seg+2] = bf2f(vu.z); Vs[key][seg+3] = bf2f(vu.w);
        }
        __syncthreads();

        int nk = sq - ka + 1;
        if (nk > 64) nk = 64;
        for (int kk = 0; kk < nk; ++kk) {
            float dot = 0.f;
#pragma unroll
            for (int d = 0; d < 64; ++d) dot += q[d] * Ks[kk][d];
            float p = expf(dot);
            l += p;
#pragma unroll
            for (int d = 0; d < 64; ++d) acc[d] += p * Vs[kk][d];
        }
    }

    float rl = 1.0f / l;
    size_t ooff = ((size_t)b * S_ + sq) * HID + h * 64;
#pragma unroll
    for (int d = 0; d < 64; d += 4) {
        ushort4 s;
        s.x = f2bf(acc[d]   * rl); s.y = f2bf(acc[d+1] * rl);
        s.z = f2bf(acc[d+2] * rl); s.w = f2bf(acc[d+3] * rl);
        *(ushort4*)(Om + ooff + d) = s;
    }
}

// ---------------------------------------------------------------------------
// X16 = LayerNorm(T16 + X16) * g + b   (bf16 residual stream, fp32 math)
// ---------------------------------------------------------------------------
__global__ __launch_bounds__(256) void k_addln(const u16* __restrict__ T,
                                               u16* __restrict__ X16,
                                               const float* __restrict__ g,
                                               const float* __restrict__ bb) {
    __shared__ float red[8];
    int r = blockIdx.x;
    size_t off = (size_t)r * HID;
    int tid = threadIdx.x;
    int c0 = tid << 1;
    ushort2 tv = *(const ushort2*)(T + off + c0);
    ushort2 xv = *(const ushort2*)(X16 + off + c0);
    float v0 = bf2f(tv.x) + bf2f(xv.x);
    float v1 = bf2f(tv.y) + bf2f(xv.y);
    float s  = v0 + v1;
    float sq = v0 * v0 + v1 * v1;
#pragma unroll
    for (int o = 32; o > 0; o >>= 1) {
        s  += __shfl_down(s,  o, 64);
        sq += __shfl_down(sq, o, 64);
    }
    int wid = tid >> 6;
    if ((tid & 63) == 0) { red[wid] = s; red[4 + wid] = sq; }
    __syncthreads();
    if (tid == 0) {
        red[0] = red[0] + red[1] + red[2] + red[3];
        red[4] = red[4] + red[5] + red[6] + red[7];
    }
    __syncthreads();
    float mean = red[0] * (1.0f / 512.0f);
    float var  = red[4] * (1.0f / 512.0f) - mean * mean;
    float rs   = rsqrtf(var + 1e-6f);
    float2 gv = *(const float2*)(g + c0);
    float2 bv = *(const float2*)(bb + c0);
    ushort2 o;
    o.x = f2bf((v0 - mean) * rs * gv.x + bv.x);
    o.y = f2bf((v1 - mean) * rs * gv.y + bv.y);
    *(ushort2*)(X16 + off + c0) = o;
}

// ---------------------------------------------------------------------------
// Fallback-path add+LN (fp32 residual) — round-10 logic.
// ---------------------------------------------------------------------------
__global__ __launch_bounds__(256) void k_addln_fb(const u16* __restrict__ T,
                                                  float* __restrict__ X,
                                                  const float* __restrict__ g,
                                                  const float* __restrict__ bb) {
    __shared__ float red[8];
    int r = blockIdx.x;
    size_t off = (size_t)r * HID;
    int tid = threadIdx.x;
    float v0 = bf2f(T[off + tid])       + X[off + tid];
    float v1 = bf2f(T[off + tid + 256]) + X[off + tid + 256];
    float s  = v0 + v1;
    float sq = v0 * v0 + v1 * v1;
#pragma unroll
    for (int o = 32; o > 0; o >>= 1) {
        s  += __shfl_down(s,  o, 64);
        sq += __shfl_down(sq, o, 64);
    }
    int wid = tid >> 6;
    if ((tid & 63) == 0) { red[wid] = s; red[4 + wid] = sq; }
    __syncthreads();
    if (tid == 0) {
        red[0] = red[0] + red[1] + red[2] + red[3];
        red[4] = red[4] + red[5] + red[6] + red[7];
    }
    __syncthreads();
    float mean = red[0] * (1.0f / 512.0f);
    float var  = red[4] * (1.0f / 512.0f) - mean * mean;
    float rs   = rsqrtf(var + 1e-6f);
    X[off + tid]       = (v0 - mean) * rs * g[tid]       + bb[tid];
    X[off + tid + 256] = (v1 - mean) * rs * g[tid + 256] + bb[tid + 256];
}

// ---------------------------------------------------------------------------
// Fallback embed (fp32 out) — round-10 logic.
// ---------------------------------------------------------------------------
__global__ __launch_bounds__(256) void k_embed_fb(const float* __restrict__ X,
                                                  const float* __restrict__ emb,
                                                  float* __restrict__ xo) {
    int r = blockIdx.x;
    int b = r / S_, s = r - b * S_;
    int h = s / (W_ * C_);
    int j = s - h * (W_ * C_);
    int tid = threadIdx.x;

    float e0 = 0.f, e1 = 0.f;
    if (s > 0) {
        int sp = s - 1;
        int hp = sp / (W_ * C_);
        int jp = sp - hp * (W_ * C_);
        int cp = jp % C_;
        int wp = jp / C_;
        float xv = X[(((size_t)b * C_ + cp) * H_ + hp) * W_ + wp];
        int iv = (int)(xv * 255.0f) + cp * NPIX;
        const float* er = emb + (size_t)iv * HID;
        e0 = er[tid]       * 22.627416997969522f;
        e1 = er[tid + 256] * 22.627416997969522f;
    }
    float invd = expf((float)(tid & 127) * -0.07252236513366287f);
    float p0 = (tid < 128) ? sinf((float)h * invd) : cosf((float)h * invd);
    float p1 = (tid < 128) ? sinf((float)j * invd) : cosf((float)j * invd);

    xo[(size_t)r * HID + tid]       = e0 + p0;
    xo[(size_t)r * HID + tid + 256] = e1 + p1;
}

// ---------------------------------------------------------------------------
// (B,S,NPIX) fp32 logits -> (B,C,H,W,NPIX) fp32 output (fallback only)
// ---------------------------------------------------------------------------
__global__ __launch_bounds__(256) void k_permute(const float* __restrict__ T,
                                                 float* __restrict__ O) {
    int r = blockIdx.x;
    int p = threadIdx.x;
    int b = r / S_, s = r - b * S_;
    int h = s / (W_ * C_);
    int j = s - h * (W_ * C_);
    int w = j / C_;
    int c = j - w * C_;
    O[((((size_t)b * C_ + c) * H_ + h) * W_ + w) * NPIX + p] =
        T[(size_t)r * NPIX + p];
}

// ---------------------------------------------------------------------------
extern "C" void kernel_launch(void* const* d_in, const int* in_sizes, int n_in,
                              void* d_out, int out_size, void* d_ws, size_t ws_size,
                              hipStream_t stream) {
    const float* X    = (const float*)d_in[0];
    const float* emb  = (const float*)d_in[1];
    const float* Wq   = (const float*)d_in[2];
    const float* Wk   = (const float*)d_in[3];
    const float* Wv   = (const float*)d_in[4];
    const float* Wo   = (const float*)d_in[5];
    const float* g1   = (const float*)d_in[6];
    const float* b1l  = (const float*)d_in[7];
    const float* W1   = (const float*)d_in[8];
    const float* bb1  = (const float*)d_in[9];
    const float* W2   = (const float*)d_in[10];
    const float* bb2  = (const float*)d_in[11];
    const float* g2   = (const float*)d_in[12];
    const float* b2l  = (const float*)d_in[13];
    const float* Wout = (const float*)d_in[14];
    const float* bout = (const float*)d_in[15];
    float* out = (float*)d_out;
    (void)in_sizes; (void)n_in; (void)out_size;

    const size_t NB = (size_t)MROWS * HID;
    const size_t BIG_NEED = 189005824ull;   // proven fault-free footprint

    if (ws_size >= BIG_NEED) {
        // ===== BIG PATH (bf16 residual stream, dbuf 128x128 GEMM) =====
        u16* x16    = (u16*)d_ws;
        u16* q16    = x16 + NB;
        u16* k16    = q16 + NB;
        u16* v16    = k16 + NB;
        u16* hxA    = v16 + NB;            // hidden tail (q16..hxA = 4*NB)
        u16* hxB    = hxA + NB;            // FFN2 output (disjoint from hidden)
        u16* wqkvT  = hxB + NB;
        u16* woT    = wqkvT + (size_t)6 * 1536 * 512;
        u16* w1T    = woT   + (size_t)6 * 512 * 512;
        u16* w2T    = w1T   + (size_t)6 * 2048 * 512;
        u16* woutT  = w2T   + (size_t)6 * 512 * 2048;
        u16* h16    = q16;                 // full FFN hidden = q16..hxA span

        k_trans_g<<<dim3(8, 8, 6),  256, 0, stream>>>(Wq, wqkvT,          512, 512,  262144, 786432);
        k_trans_g<<<dim3(8, 8, 6),  256, 0, stream>>>(Wk, wqkvT + 262144, 512, 512,  262144, 786432);
        k_trans_g<<<dim3(8, 8, 6),  256, 0, stream>>>(Wv, wqkvT + 524288, 512, 512,  262144, 786432);
        k_trans_g<<<dim3(8, 8, 6),  256, 0, stream>>>(Wo, woT,            512, 512,  262144, 262144);
        k_trans_g<<<dim3(32, 8, 6), 256, 0, stream>>>(W1, w1T,  2048, 512, 1048576, 1048576);
        k_trans_g<<<dim3(8, 32, 6), 256, 0, stream>>>(W2, w2T,  512, 2048, 1048576, 1048576);
        k_trans_g<<<dim3(4, 8, 1),  256, 0, stream>>>(Wout, woutT, 256, 512, 131072, 131072);

        k_embed<<<MROWS, 256, 0, stream>>>(X, emb, x16);

        for (int i = 0; i < L_; ++i) {
            // QKV: nx=12, ny=192 -> 2304 blocks
            g_bf16<1,1,0,0,0,512><<<2304, 256, 0, stream>>>(
                x16, wqkvT + (size_t)i * 1536 * 512, nullptr,
                q16, k16, v16, HID, 12);

            k_attn_mfma<<<768, 256, 0, stream>>>(q16, k16, v16, q16);

            // O-proj: nx=4, ny=192 -> 768 blocks
            g_bf16<0,1,0,0,0,512><<<768, 256, 0, stream>>>(
                q16, woT + (size_t)i * 512 * 512, nullptr,
                k16, nullptr, nullptr, HID, 4);
            k_addln<<<MROWS, 256, 0, stream>>>(k16, x16,
                                               g1 + i * HID, b1l + i * HID);

            // FFN1 (merged M=24576): nx=16, ny=192 -> 3072 blocks
            g_bf16<0,1,1,1,0,512><<<3072, 256, 0, stream>>>(
                x16, w1T + (size_t)i * 2048 * 512,
                bb1 + i * FILT, h16, nullptr, nullptr, FILT, 16);
            // FFN2 (merged, K=2048): nx=4, ny=192 -> 768 blocks -> hxB
            g_bf16<0,1,1,0,0,2048><<<768, 256, 0, stream>>>(
                h16, w2T + (size_t)i * 512 * 2048,
                bb2 + i * HID, hxB, nullptr, nullptr, HID, 4);

            k_addln<<<MROWS, 256, 0, stream>>>(hxB, x16,
                                               g2 + i * HID, b2l + i * HID);
        }

        // out-proj with fused permute: nx=2, ny=192 -> 384 blocks
        g_bf16<0,0,1,0,1,512><<<384, 256, 0, stream>>>(
            x16, woutT, bout, out, nullptr, nullptr, NPIX, 2);

    } else {
        // ===== FALLBACK: round-10 proven path (fp32 residual) =====
        float* x32 = (float*)d_ws;
        u16*   q16 = (u16*)(x32 + NB);
        u16*   k16 = q16 + NB;
        u16*   v16 = k16 + NB;
        u16*   hid16  = q16;
        float* logits = (float*)q16;

        k_embed_fb<<<MROWS, 256, 0, stream>>>(X, emb, x32);

        dim3 gQKV(HID / 128, MROWS / 128);
        dim3 gW1(FILT / 128, (MROWS / 2) / 128);
        dim3 gW2(HID / 128, (MROWS / 2) / 128);
        dim3 gOut(NPIX / 128, MROWS / 128);

        for (int i = 0; i < L_; ++i) {
            const float* wq = Wq + (size_t)i * HID * HID;
            const float* wk = Wk + (size_t)i * HID * HID;
            const float* wv = Wv + (size_t)i * HID * HID;
            const float* wo = Wo + (size_t)i * HID * HID;

            g_mfma<0,1,0,0><<<gQKV, 256, 0, stream>>>(x32, wq, nullptr, q16, HID, HID);
            g_mfma<0,1,0,0><<<gQKV, 256, 0, stream>>>(x32, wk, nullptr, k16, HID, HID);
            g_mfma<0,1,0,0><<<gQKV, 256, 0, stream>>>(x32, wv, nullptr, v16, HID, HID);

            k_attn<<<dim3(S_ / BLEN, B_ * HEADS), 256, 0, stream>>>(q16, k16, v16, q16);

            g_mfma<1,1,0,0><<<gQKV, 256, 0, stream>>>(q16, wo, nullptr, k16, HID, HID);
            k_addln_fb<<<MROWS, 256, 0, stream>>>(k16, x32,
                                                  g1 + i * HID, b1l + i * HID);

            for (int c = 0; c < 2; ++c) {
                const size_t r0 = (size_t)c * (MROWS / 2);
                g_mfma<0,1,1,1><<<gW1, 256, 0, stream>>>(
                    x32 + r0 * HID, W1 + (size_t)i * HID * FILT,
                    bb1 + i * FILT, hid16, FILT, HID);
                g_mfma<1,1,1,0><<<gW2, 256, 0, stream>>>(
                    hid16, W2 + (size_t)i * FILT * HID,
                    bb2 + i * HID, v16 + r0 * HID, HID, FILT);
            }
            k_addln_fb<<<MROWS, 256, 0, stream>>>(v16, x32,
                                                  g2 + i * HID, b2l + i * HID);
        }

        g_mfma<0,0,1,0><<<gOut, 256, 0, stream>>>(x32, Wout, bout, logits, NPIX, HID);
        k_permute<<<MROWS, 256, 0, stream>>>(logits, out);
    }
}

// Round 21
// 1901.354 us; speedup vs baseline: 1.0086x; 1.0086x over previous
//
#include <hip/hip_runtime.h>
#include <hip/hip_bf16.h>
#include <cstdint>

#define B_    8
#define C_    3
#define H_    32
#define W_    32
#define HID   512
#define HEADS 8
#define FILT  2048
#define L_    6
#define BLEN  256
#define NPIX  256
#define S_    (H_*W_*C_)   /* 3072 */
#define MROWS (B_*S_)      /* 24576 */

typedef unsigned short u16;
typedef short bf16x8 __attribute__((ext_vector_type(8)));
typedef float f32x4  __attribute__((ext_vector_type(4)));

__device__ __forceinline__ float bf2f(u16 u) {
    union { unsigned int i; float f; } x; x.i = ((unsigned int)u) << 16; return x.f;
}
__device__ __forceinline__ u16 f2bf(float f) {
    __hip_bfloat16 h = __float2bfloat16(f);
    return *reinterpret_cast<u16*>(&h);
}

#define GLP(p) ((const __attribute__((address_space(1))) void*)(p))
#define LLP(p) ((__attribute__((address_space(3))) void*)(p))

// ---------------------------------------------------------------------------
// Embedding gather + shift + positional -> x16 (bf16 residual stream).
// ---------------------------------------------------------------------------
__global__ __launch_bounds__(256) void k_embed(const float* __restrict__ X,
                                               const float* __restrict__ emb,
                                               u16* __restrict__ xo16) {
    int r = blockIdx.x;              // b*S + s
    int b = r / S_, s = r - b * S_;
    int h = s / (W_ * C_);
    int j = s - h * (W_ * C_);
    int tid = threadIdx.x;
    int d0 = tid << 1;               // 0,2,..,510

    float e0 = 0.f, e1 = 0.f;
    if (s > 0) {
        int sp = s - 1;
        int hp = sp / (W_ * C_);
        int jp = sp - hp * (W_ * C_);
        int cp = jp % C_;
        int wp = jp / C_;
        float xv = X[(((size_t)b * C_ + cp) * H_ + hp) * W_ + wp];
        int iv = (int)(xv * 255.0f) + cp * NPIX;
        float2 ev = *(const float2*)(emb + (size_t)iv * HID + d0);
        e0 = ev.x * 22.627416997969522f;   // sqrt(512)
        e1 = ev.y * 22.627416997969522f;
    }
    float p01[2];
#pragma unroll
    for (int q = 0; q < 2; ++q) {
        int d = d0 + q;
        float invd = expf((float)(d & 127) * -0.07252236513366287f);
        p01[q] = (d < 128) ? sinf((float)h * invd)
               : (d < 256) ? cosf((float)h * invd)
               : (d < 384) ? sinf((float)j * invd)
                           : cosf((float)j * invd);
    }
    ushort2 o;
    o.x = f2bf(e0 + p01[0]);
    o.y = f2bf(e1 + p01[1]);
    *(ushort2*)(xo16 + (size_t)r * HID + d0) = o;
}

// ---------------------------------------------------------------------------
// 64x64 tile transpose+convert: out[N][K] (bf16) = in[K][N] (fp32).
// ---------------------------------------------------------------------------
__global__ __launch_bounds__(256) void k_trans_g(const float* __restrict__ in,
                                                 u16* __restrict__ out,
                                                 int N, int K,
                                                 size_t inStride, size_t outStride) {
    __shared__ u16 T[64][72];
    in  += (size_t)blockIdx.z * inStride;
    out += (size_t)blockIdx.z * outStride;
    int n0 = blockIdx.x * 64, k0 = blockIdx.y * 64;
    int t = threadIdx.x;
    int r4 = t >> 4;            // 0..15
    int c4 = (t & 15) << 2;     // 0..60
#pragma unroll
    for (int pass = 0; pass < 4; ++pass) {
        int kr = pass * 16 + r4;
        float4 v = *(const float4*)(in + (size_t)(k0 + kr) * N + n0 + c4);
        T[c4 + 0][kr] = f2bf(v.x);
        T[c4 + 1][kr] = f2bf(v.y);
        T[c4 + 2][kr] = f2bf(v.z);
        T[c4 + 3][kr] = f2bf(v.w);
    }
    __syncthreads();
#pragma unroll
    for (int pass = 0; pass < 4; ++pass) {
        int n = pass * 16 + r4;
        ushort4 s = {T[n][c4], T[n][c4 + 1], T[n][c4 + 2], T[n][c4 + 3]};
        *(ushort4*)(out + (size_t)(n0 + n) * K + k0 + c4) = s;
    }
}

// ---------------------------------------------------------------------------
// Pure-bf16 MFMA GEMM, 256x128 tile, 8 waves (512 thr), BK=64, single-buffer
// (proven round-19 configuration: implicit wave-level overlap at 3 blocks/CU
// beats explicit dbuf at 2 blocks/CU — round-20 A/B).
// C = A(M,K) @ Bt(N,K)^T  [+bias][relu].  KT: compile-time K.
// XCD-aware 1D grid swizzle (nwg%8==0 at all call sites).
// ---------------------------------------------------------------------------
template<int QKV, int C_BF, int BIAS, int RELU, int PERM, int KT>
__global__ __launch_bounds__(512) void g_bf16(const u16* __restrict__ A,
                                              const u16* __restrict__ Bt,
                                              const float* __restrict__ bias,
                                              void* __restrict__ C0,
                                              void* __restrict__ C1,
                                              void* __restrict__ C2,
                                              int Nc, int nx) {
    __shared__ __align__(16) u16 smem[24576];   // As 16384 | Bs 8192 (49152 B)
    u16* As = smem;
    u16* Bs = smem + 16384;
    int tid  = threadIdx.x;
    int lane = tid & 63;
    int w    = tid >> 6;                 // 0..7

    int qg  = (int)gridDim.x >> 3;
    int wg  = (blockIdx.x & 7) * qg + (blockIdx.x >> 3);
    int bx  = wg % nx, by = wg / nx;
    int row0 = by * 256, col0 = bx * 128;

    int l8 = lane >> 3;                  // 0..7
    int l7 = lane & 7;                   // 0..7
    int scol = (l7 ^ l8) << 3;           // pre-swizzled source col (elems)
    const u16* aP = A  + (size_t)(row0 + w * 32 + l8) * KT + scol;
    const u16* bP = Bt + (size_t)(col0 + w * 16 + l8) * KT + scol;
    u16* asBase = As + w * 2048;         // 32 rows x 64 per wave
    u16* bsBase = Bs + w * 1024;         // 16 rows x 64 per wave

    int wr = (w >> 1) << 6;              // 0,64,128,192 (M quadrant)
    int wc = (w & 1) << 6;               // 0,64         (N quadrant)
    int lr = lane & 15;
    int kb = lane >> 4;

    f32x4 acc[4][4];
#pragma unroll
    for (int mi = 0; mi < 4; ++mi)
#pragma unroll
        for (int nj = 0; nj < 4; ++nj)
            acc[mi][nj] = (f32x4){0.f, 0.f, 0.f, 0.f};

    for (int k0 = 0; k0 < KT; k0 += 64) {
#pragma unroll
        for (int p = 0; p < 4; ++p)
            __builtin_amdgcn_global_load_lds(GLP(aP + (size_t)p * 8 * KT),
                                             LLP(asBase + p * 512), 16, 0, 0);
#pragma unroll
        for (int p = 0; p < 2; ++p)
            __builtin_amdgcn_global_load_lds(GLP(bP + (size_t)p * 8 * KT),
                                             LLP(bsBase + p * 512), 16, 0, 0);
        aP += 64; bP += 64;
        __syncthreads();

#pragma unroll
        for (int kh = 0; kh < 2; ++kh) {
            int sl = ((kh << 2) + kb) ^ (lr & 7);
            bf16x8 af[4], bv[4];
#pragma unroll
            for (int mi = 0; mi < 4; ++mi)
                af[mi] = *(const bf16x8*)&As[(wr + lr) * 64 + mi * 1024 + sl * 8];
#pragma unroll
            for (int nj = 0; nj < 4; ++nj)
                bv[nj] = *(const bf16x8*)&Bs[(wc + lr) * 64 + nj * 1024 + sl * 8];
            __builtin_amdgcn_s_setprio(1);
#pragma unroll
            for (int mi = 0; mi < 4; ++mi)
#pragma unroll
                for (int nj = 0; nj < 4; ++nj)
                    acc[mi][nj] = __builtin_amdgcn_mfma_f32_16x16x32_bf16(
                        af[mi], bv[nj], acc[mi][nj], 0, 0, 0);
            __builtin_amdgcn_s_setprio(0);
        }
        __syncthreads();
    }

    if (C_BF) {
        u16* Cp; int cbase;
        if (QKV) {
            int sel = col0 >> 9;
            Cp = (u16*)(sel == 0 ? C0 : sel == 1 ? C1 : C2);
            cbase = col0 & 511;
        } else { Cp = (u16*)C0; cbase = col0; }
#pragma unroll
        for (int pass = 0; pass < 2; ++pass) {
            if ((w >> 2) == pass) {              // waves owning rows pass*128..+127
                int rbase = wr - pass * 128;     // 0 or 64
#pragma unroll
                for (int nj = 0; nj < 4; ++nj) {
                    int colL = wc + (nj << 4) + lr;
                    float bsv = BIAS ? bias[col0 + colL] : 0.f;
#pragma unroll
                    for (int mi = 0; mi < 4; ++mi)
#pragma unroll
                        for (int reg = 0; reg < 4; ++reg) {
                            int rowL = rbase + (mi << 4) + (kb << 2) + reg;
                            float v = acc[mi][nj][reg] + bsv;
                            if (RELU) v = fmaxf(v, 0.f);
                            smem[rowL * 136 + colL] = f2bf(v);
                        }
                }
            }
            __syncthreads();
#pragma unroll
            for (int it = 0; it < 4; ++it) {
                int job  = tid + (it << 9);      // 2048 jobs = 128 rows x 16 slots
                int rowL = job >> 4;
                int colL = (job & 15) << 3;
                bf16x8 vv = *(const bf16x8*)&smem[rowL * 136 + colL];
                *(bf16x8*)(Cp + (size_t)(row0 + pass * 128 + rowL) * Nc
                               + cbase + colL) = vv;
            }
            __syncthreads();
        }
    } else {
#pragma unroll
        for (int nj = 0; nj < 4; ++nj) {
            int colg = col0 + wc + (nj << 4) + lr;
            float bsv = BIAS ? bias[colg] : 0.f;
#pragma unroll
            for (int mi = 0; mi < 4; ++mi)
#pragma unroll
                for (int reg = 0; reg < 4; ++reg) {
                    int row = row0 + wr + (mi << 4) + (kb << 2) + reg;
                    float v = acc[mi][nj][reg] + bsv;
                    if (RELU) v = fmaxf(v, 0.f);
                    if (PERM) {
                        int bb = row / S_;
                        int ss = row - bb * S_;
                        int hh = ss / (W_ * C_);
                        int jj = ss - hh * (W_ * C_);
                        int ww = jj / C_;
                        int cc = jj - ww * C_;
                        ((float*)C0)[((((size_t)bb * C_ + cc) * H_ + hh) * W_ + ww)
                                     * NPIX + colg] = v;
                    } else {
                        ((float*)C0)[(size_t)row * Nc + colg] = v;
                    }
                }
        }
    }
}

// ---------------------------------------------------------------------------
// LEGACY fp32-staged MFMA GEMM — fallback path only.
// ---------------------------------------------------------------------------
template<int A_BF, int C_BF, int BIAS, int RELU>
__global__ __launch_bounds__(256) void g_mfma(const void* __restrict__ Ap,
                                              const float* __restrict__ Bw,
                                              const float* __restrict__ bias,
                                              void* __restrict__ Cp,
                                              int N, int K) {
    __shared__ __align__(16) u16 As[128][40];
    __shared__ __align__(16) u16 Bs[128][40];
    int tid  = threadIdx.x;
    int row0 = blockIdx.y * 128, col0 = blockIdx.x * 128;

    int ar  = tid >> 1;
    int akq = (tid & 1) << 4;
    int bkk = tid >> 5;
    int bnn = (tid & 31) << 2;

    int lane = tid & 63;
    int wv   = tid >> 6;
    int wr   = (wv >> 1) << 6;
    int wc   = (wv & 1) << 6;
    int lr   = lane & 15;
    int kb   = lane >> 4;

    f32x4 acc[4][4];
#pragma unroll
    for (int mi = 0; mi < 4; ++mi)
#pragma unroll
        for (int nj = 0; nj < 4; ++nj)
            acc[mi][nj] = (f32x4){0.f, 0.f, 0.f, 0.f};

    for (int k0 = 0; k0 < K; k0 += 32) {
        if (A_BF) {
            const u16* ap = (const u16*)Ap + (size_t)(row0 + ar) * K + k0 + akq;
#pragma unroll
            for (int p = 0; p < 4; ++p)
                *(ushort4*)&As[ar][akq + (p << 2)] = *(const ushort4*)(ap + (p << 2));
        } else {
            const float* ap = (const float*)Ap + (size_t)(row0 + ar) * K + k0 + akq;
#pragma unroll
            for (int p = 0; p < 4; ++p) {
                float4 v = *(const float4*)(ap + (p << 2));
                ushort4 wq = {f2bf(v.x), f2bf(v.y), f2bf(v.z), f2bf(v.w)};
                *(ushort4*)&As[ar][akq + (p << 2)] = wq;
            }
        }
#pragma unroll
        for (int p = 0; p < 4; ++p) {
            int kl = bkk + (p << 3);
            float4 wv4 = *(const float4*)(Bw + (size_t)(k0 + kl) * N + col0 + bnn);
            Bs[bnn + 0][kl] = f2bf(wv4.x);
            Bs[bnn + 1][kl] = f2bf(wv4.y);
            Bs[bnn + 2][kl] = f2bf(wv4.z);
            Bs[bnn + 3][kl] = f2bf(wv4.w);
        }
        __syncthreads();

        bf16x8 af[4], bfr[4];
#pragma unroll
        for (int mi = 0; mi < 4; ++mi)
            af[mi] = *(const bf16x8*)&As[wr + (mi << 4) + lr][kb << 3];
#pragma unroll
        for (int nj = 0; nj < 4; ++nj)
            bfr[nj] = *(const bf16x8*)&Bs[wc + (nj << 4) + lr][kb << 3];
#pragma unroll
        for (int mi = 0; mi < 4; ++mi)
#pragma unroll
            for (int nj = 0; nj < 4; ++nj)
                acc[mi][nj] = __builtin_amdgcn_mfma_f32_16x16x32_bf16(
                    af[mi], bfr[nj], acc[mi][nj], 0, 0, 0);
        __syncthreads();
    }

#pragma unroll
    for (int mi = 0; mi < 4; ++mi)
#pragma unroll
        for (int nj = 0; nj < 4; ++nj) {
            int col = col0 + wc + (nj << 4) + lr;
            float bsv = BIAS ? bias[col] : 0.f;
#pragma unroll
            for (int reg = 0; reg < 4; ++reg) {
                int row = row0 + wr + (mi << 4) + (kb << 2) + reg;
                float v = acc[mi][nj][reg] + bsv;
                if (RELU) v = fmaxf(v, 0.f);
                if (C_BF)
                    ((u16*)Cp)[(size_t)row * N + col] = f2bf(v);
                else
                    ((float*)Cp)[(size_t)row * N + col] = v;
            }
        }
}

// ---------------------------------------------------------------------------
// MFMA flash-style block-local causal attention (bf16), SWAPPED QK^T,
// XCD-aware 1D grid + K/V register prefetch.  (proven round-15 form)
// ---------------------------------------------------------------------------
__global__ __launch_bounds__(256) void k_attn_mfma(const u16* Qm,
                                                   const u16* __restrict__ Km,
                                                   const u16* __restrict__ Vm,
                                                   u16* Om) {
    __shared__ __align__(16) u16 Kl[64][72];      // [key][d]
    __shared__ __align__(16) u16 VT[64][72];      // [d][key^vsw]
    __shared__ __align__(16) u16 Pl[4][64][64];   // per-wave [q][k^((q&7)<<3)]

    int f   = blockIdx.x;            // 0..767
    int xcd = f & 7;
    int t2  = f >> 3;
    int qb  = t2 % 12;
    int grp = t2 / 12;               // 0..7
    int bh  = (grp << 3) | xcd;
    int b   = bh >> 3, h = bh & 7;

    int tid = threadIdx.x;
    int lane = tid & 63;
    int w    = tid >> 6;
    int lr   = lane & 15;
    int kb   = lane >> 4;            // 0..3
    int qw   = qb * BLEN + w * 64;   // wave query base
    int vsw  = (tid & 7) << 3;       // VT write swizzle
    int psw  = (lr & 7) << 3;        // Pl swizzle for this lane's rows (q&7)

    bf16x8 qf[4][2];
#pragma unroll
    for (int mi = 0; mi < 4; ++mi)
#pragma unroll
        for (int ks = 0; ks < 2; ++ks)
            qf[mi][ks] = *(const bf16x8*)(Qm +
                ((size_t)b * S_ + qw + mi * 16 + lr) * HID + h * 64 + ks * 32 + kb * 8);

    f32x4 oacc[4][4];                 // [mi][dj]
    float lacc[4];
#pragma unroll
    for (int mi = 0; mi < 4; ++mi) {
        lacc[mi] = 0.f;
#pragma unroll
        for (int dj = 0; dj < 4; ++dj)
            oacc[mi][dj] = (f32x4){0.f, 0.f, 0.f, 0.f};
    }

    int kstart = (qb == 0) ? 0 : (qb - 1) * BLEN;
    int nch    = (qb == 0) ? 4 : 8;

    int key0 = tid >> 3;
    int key1 = (tid + 256) >> 3;
    int d8   = (tid & 7) << 3;

    bf16x8 kvr0, kvr1, vvr0, vvr1;
    {
        size_t g0 = ((size_t)b * S_ + kstart + key0) * HID + h * 64 + d8;
        size_t g1 = ((size_t)b * S_ + kstart + key1) * HID + h * 64 + d8;
        kvr0 = *(const bf16x8*)(Km + g0);
        vvr0 = *(const bf16x8*)(Vm + g0);
        kvr1 = *(const bf16x8*)(Km + g1);
        vvr1 = *(const bf16x8*)(Vm + g1);
    }

    for (int ck = 0; ck < nch; ++ck) {
        int ka = kstart + ck * 64;
        __syncthreads();
        *(bf16x8*)&Kl[key0][d8] = kvr0;
        *(bf16x8*)&Kl[key1][d8] = kvr1;
        {
            const u16* vu0 = (const u16*)&vvr0;
            const u16* vu1 = (const u16*)&vvr1;
            int kc0 = key0 ^ vsw, kc1 = key1 ^ vsw;
#pragma unroll
            for (int e = 0; e < 8; ++e) VT[d8 + e][kc0] = vu0[e];
#pragma unroll
            for (int e = 0; e < 8; ++e) VT[d8 + e][kc1] = vu1[e];
        }
        __syncthreads();

        if (ck + 1 < nch) {
            int kan = ka + 64;
            size_t g0 = ((size_t)b * S_ + kan + key0) * HID + h * 64 + d8;
            size_t g1 = ((size_t)b * S_ + kan + key1) * HID + h * 64 + d8;
            kvr0 = *(const bf16x8*)(Km + g0);
            vvr0 = *(const bf16x8*)(Vm + g0);
            kvr1 = *(const bf16x8*)(Km + g1);
            vvr1 = *(const bf16x8*)(Vm + g1);
        }

        if (ka <= qw + 63) {
            f32x4 sa[4][4];
#pragma unroll
            for (int nj = 0; nj < 4; ++nj)
#pragma unroll
                for (int mi = 0; mi < 4; ++mi)
                    sa[nj][mi] = (f32x4){0.f, 0.f, 0.f, 0.f};
#pragma unroll
            for (int ks = 0; ks < 2; ++ks) {
                bf16x8 kf[4];
#pragma unroll
                for (int nj = 0; nj < 4; ++nj)
                    kf[nj] = *(const bf16x8*)&Kl[nj * 16 + lr][ks * 32 + kb * 8];
                __builtin_amdgcn_s_setprio(1);
#pragma unroll
                for (int nj = 0; nj < 4; ++nj)
#pragma unroll
                    for (int mi = 0; mi < 4; ++mi)
                        sa[nj][mi] = __builtin_amdgcn_mfma_f32_16x16x32_bf16(
                            kf[nj], qf[mi][ks], sa[nj][mi], 0, 0, 0);
                __builtin_amdgcn_s_setprio(0);
            }
            bool diag = (ka + 63 > qw);
#pragma unroll
            for (int mi = 0; mi < 4; ++mi) {
                int qg2 = qw + mi * 16 + lr;
                float tsum = 0.f;
#pragma unroll
                for (int nj = 0; nj < 4; ++nj) {
                    ushort4 pk;
                    u16* pp = (u16*)&pk;
#pragma unroll
                    for (int reg = 0; reg < 4; ++reg) {
                        float s = sa[nj][mi][reg] * 0.125f;
                        float p = __expf(s);
                        if (diag && (ka + nj * 16 + kb * 4 + reg > qg2)) p = 0.f;
                        tsum += p;
                        pp[reg] = f2bf(p);
                    }
                    *(ushort4*)&Pl[w][mi * 16 + lr][(nj * 16 + kb * 4) ^ psw] = pk;
                }
                tsum += __shfl_xor(tsum, 16);
                tsum += __shfl_xor(tsum, 32);
                lacc[mi] += tsum;
            }
#pragma unroll
            for (int ks = 0; ks < 2; ++ks) {
                bf16x8 pf[4], vf[4];
#pragma unroll
                for (int mi = 0; mi < 4; ++mi)
                    pf[mi] = *(const bf16x8*)&Pl[w][mi * 16 + lr]
                                                 [(ks * 32 + kb * 8) ^ psw];
#pragma unroll
                for (int dj = 0; dj < 4; ++dj) {
                    int vr = ((dj * 2 + (lr >> 3)) & 7) << 3;
                    vf[dj] = *(const bf16x8*)&VT[dj * 16 + lr]
                                                [(ks * 32 + kb * 8) ^ vr];
                }
                __builtin_amdgcn_s_setprio(1);
#pragma unroll
                for (int mi = 0; mi < 4; ++mi)
#pragma unroll
                    for (int dj = 0; dj < 4; ++dj)
                        oacc[mi][dj] = __builtin_amdgcn_mfma_f32_16x16x32_bf16(
                            pf[mi], vf[dj], oacc[mi][dj], 0, 0, 0);
                __builtin_amdgcn_s_setprio(0);
            }
        }
    }

#pragma unroll
    for (int mi = 0; mi < 4; ++mi) {
        float lr4[4];
#pragma unroll
        for (int reg = 0; reg < 4; ++reg)
            lr4[reg] = __shfl(lacc[mi], kb * 4 + reg);
#pragma unroll
        for (int reg = 0; reg < 4; ++reg) {
            float rl = 1.0f / lr4[reg];
            size_t orow = ((size_t)b * S_ + qw + mi * 16 + kb * 4 + reg) * HID + h * 64;
#pragma unroll
            for (int dj = 0; dj < 4; ++dj)
                Om[orow + dj * 16 + lr] = f2bf(oacc[mi][dj][reg] * rl);
        }
    }
}

// ---------------------------------------------------------------------------
// LEGACY scalar attention — fallback path only.
// ---------------------------------------------------------------------------
__global__ __launch_bounds__(256) void k_attn(const u16* Qm,
                                              const u16* __restrict__ Km,
                                              const u16* __restrict__ Vm,
                                              u16* Om) {
    __shared__ float Ks[64][64];
    __shared__ float Vs[64][64];
    int qb  = blockIdx.x;
    int bh  = blockIdx.y;
    int b   = bh >> 3, h = bh & 7;
    int tid = threadIdx.x;
    int sq  = qb * BLEN + tid;

    size_t qoff = ((size_t)b * S_ + sq) * HID + h * 64;
    float q[64];
#pragma unroll
    for (int d = 0; d < 64; d += 4) {
        ushort4 u = *(const ushort4*)(Qm + qoff + d);
        q[d]   = bf2f(u.x) * 0.125f;
        q[d+1] = bf2f(u.y) * 0.125f;
        q[d+2] = bf2f(u.z) * 0.125f;
        q[d+3] = bf2f(u.w) * 0.125f;
    }

    float acc[64];
#pragma unroll
    for (int d = 0; d < 64; ++d) acc[d] = 0.f;
    float l = 0.f;

    int kstart  = (qb == 0) ? 0 : (qb - 1) * BLEN;
    int nchunks = (qb == 0) ? 4 : 8;

    for (int ck = 0; ck < nchunks; ++ck) {
        int ka = kstart + ck * 64;
        __syncthreads();
        int li = tid;
#pragma unroll
        for (int it = 0; it < 4; ++it, li += 256) {
            int key = li >> 4;
            int seg = (li & 15) * 4;
            size_t goff = ((size_t)b * S_ + ka + key) * HID + h * 64 + seg;
            ushort4 ku = *(const ushort4*)(Km + goff);
            ushort4 vu = *(const ushort4*)(Vm + goff);
            Ks[key][seg+0] = bf2f(ku.x); Ks[key][seg+1] = bf2f(ku.y);
            Ks[key][seg+2] = bf2f(ku.z); Ks[key][seg+3] = bf2f(ku.w);
            Vs[key][seg+0] = bf2f(vu.x); Vs[key][seg+1] = bf2f(vu.y);
            Vs[key][seg+2] = bf2f(vu.z); Vs[key][seg+3] = bf2f(vu.w);
        }
        __syncthreads();

        int nk = sq - ka + 1;
        if (nk > 64) nk = 64;
        for (int kk = 0; kk < nk; ++kk) {
            float dot = 0.f;
#pragma unroll
            for (int d = 0; d < 64; ++d) dot += q[d] * Ks[kk][d];
            float p = expf(dot);
            l += p;
#pragma unroll
            for (int d = 0; d < 64; ++d) acc[d] += p * Vs[kk][d];
        }
    }

    float rl = 1.0f / l;
    size_t ooff = ((size_t)b * S_ + sq) * HID + h * 64;
#pragma unroll
    for (int d = 0; d < 64; d += 4) {
        ushort4 s;
        s.x = f2bf(acc[d]   * rl); s.y = f2bf(acc[d+1] * rl);
        s.z = f2bf(acc[d+2] * rl); s.w = f2bf(acc[d+3] * rl);
        *(ushort4*)(Om + ooff + d) = s;
    }
}

// ---------------------------------------------------------------------------
// X16 = LayerNorm(T16 + X16) * g + b   (bf16 residual stream, fp32 math)
// ---------------------------------------------------------------------------
__global__ __launch_bounds__(256) void k_addln(const u16* __restrict__ T,
                                               u16* __restrict__ X16,
                                               const float* __restrict__ g,
                                               const float* __restrict__ bb) {
    __shared__ float red[8];
    int r = blockIdx.x;
    size_t off = (size_t)r * HID;
    int tid = threadIdx.x;
    int c0 = tid << 1;
    ushort2 tv = *(const ushort2*)(T + off + c0);
    ushort2 xv = *(const ushort2*)(X16 + off + c0);
    float v0 = bf2f(tv.x) + bf2f(xv.x);
    float v1 = bf2f(tv.y) + bf2f(xv.y);
    float s  = v0 + v1;
    float sq = v0 * v0 + v1 * v1;
#pragma unroll
    for (int o = 32; o > 0; o >>= 1) {
        s  += __shfl_down(s,  o, 64);
        sq += __shfl_down(sq, o, 64);
    }
    int wid = tid >> 6;
    if ((tid & 63) == 0) { red[wid] = s; red[4 + wid] = sq; }
    __syncthreads();
    if (tid == 0) {
        red[0] = red[0] + red[1] + red[2] + red[3];
        red[4] = red[4] + red[5] + red[6] + red[7];
    }
    __syncthreads();
    float mean = red[0] * (1.0f / 512.0f);
    float var  = red[4] * (1.0f / 512.0f) - mean * mean;
    float rs   = rsqrtf(var + 1e-6f);
    float2 gv = *(const float2*)(g + c0);
    float2 bv = *(const float2*)(bb + c0);
    ushort2 o;
    o.x = f2bf((v0 - mean) * rs * gv.x + bv.x);
    o.y = f2bf((v1 - mean) * rs * gv.y + bv.y);
    *(ushort2*)(X16 + off + c0) = o;
}

// ---------------------------------------------------------------------------
// Fallback-path add+LN (fp32 residual) — round-10 logic.
// ---------------------------------------------------------------------------
__global__ __launch_bounds__(256) void k_addln_fb(const u16* __restrict__ T,
                                                  float* __restrict__ X,
                                                  const float* __restrict__ g,
                                                  const float* __restrict__ bb) {
    __shared__ float red[8];
    int r = blockIdx.x;
    size_t off = (size_t)r * HID;
    int tid = threadIdx.x;
    float v0 = bf2f(T[off + tid])       + X[off + tid];
    float v1 = bf2f(T[off + tid + 256]) + X[off + tid + 256];
    float s  = v0 + v1;
    float sq = v0 * v0 + v1 * v1;
#pragma unroll
    for (int o = 32; o > 0; o >>= 1) {
        s  += __shfl_down(s,  o, 64);
        sq += __shfl_down(sq, o, 64);
    }
    int wid = tid >> 6;
    if ((tid & 63) == 0) { red[wid] = s; red[4 + wid] = sq; }
    __syncthreads();
    if (tid == 0) {
        red[0] = red[0] + red[1] + red[2] + red[3];
        red[4] = red[4] + red[5] + red[6] + red[7];
    }
    __syncthreads();
    float mean = red[0] * (1.0f / 512.0f);
    float var  = red[4] * (1.0f / 512.0f) - mean * mean;
    float rs   = rsqrtf(var + 1e-6f);
    X[off + tid]       = (v0 - mean) * rs * g[tid]       + bb[tid];
    X[off + tid + 256] = (v1 - mean) * rs * g[tid + 256] + bb[tid + 256];
}

// ---------------------------------------------------------------------------
// Fallback embed (fp32 out) — round-10 logic.
// ---------------------------------------------------------------------------
__global__ __launch_bounds__(256) void k_embed_fb(const float* __restrict__ X,
                                                  const float* __restrict__ emb,
                                                  float* __restrict__ xo) {
    int r = blockIdx.x;
    int b = r / S_, s = r - b * S_;
    int h = s / (W_ * C_);
    int j = s - h * (W_ * C_);
    int tid = threadIdx.x;

    float e0 = 0.f, e1 = 0.f;
    if (s > 0) {
        int sp = s - 1;
        int hp = sp / (W_ * C_);
        int jp = sp - hp * (W_ * C_);
        int cp = jp % C_;
        int wp = jp / C_;
        float xv = X[(((size_t)b * C_ + cp) * H_ + hp) * W_ + wp];
        int iv = (int)(xv * 255.0f) + cp * NPIX;
        const float* er = emb + (size_t)iv * HID;
        e0 = er[tid]       * 22.627416997969522f;
        e1 = er[tid + 256] * 22.627416997969522f;
    }
    float invd = expf((float)(tid & 127) * -0.07252236513366287f);
    float p0 = (tid < 128) ? sinf((float)h * invd) : cosf((float)h * invd);
    float p1 = (tid < 128) ? sinf((float)j * invd) : cosf((float)j * invd);

    xo[(size_t)r * HID + tid]       = e0 + p0;
    xo[(size_t)r * HID + tid + 256] = e1 + p1;
}

// ---------------------------------------------------------------------------
// (B,S,NPIX) fp32 logits -> (B,C,H,W,NPIX) fp32 output (fallback only)
// ---------------------------------------------------------------------------
__global__ __launch_bounds__(256) void k_permute(const float* __restrict__ T,
                                                 float* __restrict__ O) {
    int r = blockIdx.x;
    int p = threadIdx.x;
    int b = r / S_, s = r - b * S_;
    int h = s / (W_ * C_);
    int j = s - h * (W_ * C_);
    int w = j / C_;
    int c = j - w * C_;
    O[((((size_t)b * C_ + c) * H_ + h) * W_ + w) * NPIX + p] =
        T[(size_t)r * NPIX + p];
}

// ---------------------------------------------------------------------------
extern "C" void kernel_launch(void* const* d_in, const int* in_sizes, int n_in,
                              void* d_out, int out_size, void* d_ws, size_t ws_size,
                              hipStream_t stream) {
    const float* X    = (const float*)d_in[0];
    const float* emb  = (const float*)d_in[1];
    const float* Wq   = (const float*)d_in[2];
    const float* Wk   = (const float*)d_in[3];
    const float* Wv   = (const float*)d_in[4];
    const float* Wo   = (const float*)d_in[5];
    const float* g1   = (const float*)d_in[6];
    const float* b1l  = (const float*)d_in[7];
    const float* W1   = (const float*)d_in[8];
    const float* bb1  = (const float*)d_in[9];
    const float* W2   = (const float*)d_in[10];
    const float* bb2  = (const float*)d_in[11];
    const float* g2   = (const float*)d_in[12];
    const float* b2l  = (const float*)d_in[13];
    const float* Wout = (const float*)d_in[14];
    const float* bout = (const float*)d_in[15];
    float* out = (float*)d_out;
    (void)in_sizes; (void)n_in; (void)out_size;

    const size_t NB = (size_t)MROWS * HID;
    const size_t BIG_NEED = 189005824ull;   // proven fault-free footprint

    if (ws_size >= BIG_NEED) {
        // ===== BIG PATH (bf16 residual stream, 256x128 8-wave GEMM) =====
        u16* x16    = (u16*)d_ws;
        u16* q16    = x16 + NB;
        u16* k16    = q16 + NB;
        u16* v16    = k16 + NB;
        u16* hxA    = v16 + NB;            // hidden tail (q16..hxA = 4*NB)
        u16* hxB    = hxA + NB;            // FFN2 output (disjoint from hidden)
        u16* wqkvT  = hxB + NB;
        u16* woT    = wqkvT + (size_t)6 * 1536 * 512;
        u16* w1T    = woT   + (size_t)6 * 512 * 512;
        u16* w2T    = w1T   + (size_t)6 * 2048 * 512;
        u16* woutT  = w2T   + (size_t)6 * 512 * 2048;
        u16* h16    = q16;                 // full FFN hidden = q16..hxA span

        k_trans_g<<<dim3(8, 8, 6),  256, 0, stream>>>(Wq, wqkvT,          512, 512,  262144, 786432);
        k_trans_g<<<dim3(8, 8, 6),  256, 0, stream>>>(Wk, wqkvT + 262144, 512, 512,  262144, 786432);
        k_trans_g<<<dim3(8, 8, 6),  256, 0, stream>>>(Wv, wqkvT + 524288, 512, 512,  262144, 786432);
        k_trans_g<<<dim3(8, 8, 6),  256, 0, stream>>>(Wo, woT,            512, 512,  262144, 262144);
        k_trans_g<<<dim3(32, 8, 6), 256, 0, stream>>>(W1, w1T,  2048, 512, 1048576, 1048576);
        k_trans_g<<<dim3(8, 32, 6), 256, 0, stream>>>(W2, w2T,  512, 2048, 1048576, 1048576);
        k_trans_g<<<dim3(4, 8, 1),  256, 0, stream>>>(Wout, woutT, 256, 512, 131072, 131072);

        k_embed<<<MROWS, 256, 0, stream>>>(X, emb, x16);

        for (int i = 0; i < L_; ++i) {
            // QKV: nx=12, ny=96 -> 1152 blocks x 512 thr
            g_bf16<1,1,0,0,0,512><<<1152, 512, 0, stream>>>(
                x16, wqkvT + (size_t)i * 1536 * 512, nullptr,
                q16, k16, v16, HID, 12);

            k_attn_mfma<<<768, 256, 0, stream>>>(q16, k16, v16, q16);

            // O-proj: nx=4, ny=96 -> 384 blocks
            g_bf16<0,1,0,0,0,512><<<384, 512, 0, stream>>>(
                q16, woT + (size_t)i * 512 * 512, nullptr,
                k16, nullptr, nullptr, HID, 4);
            k_addln<<<MROWS, 256, 0, stream>>>(k16, x16,
                                               g1 + i * HID, b1l + i * HID);

            // FFN1 (merged M=24576): nx=16, ny=96 -> 1536 blocks
            g_bf16<0,1,1,1,0,512><<<1536, 512, 0, stream>>>(
                x16, w1T + (size_t)i * 2048 * 512,
                bb1 + i * FILT, h16, nullptr, nullptr, FILT, 16);
            // FFN2 (merged, K=2048): nx=4, ny=96 -> 384 blocks -> hxB
            g_bf16<0,1,1,0,0,2048><<<384, 512, 0, stream>>>(
                h16, w2T + (size_t)i * 512 * 2048,
                bb2 + i * HID, hxB, nullptr, nullptr, HID, 4);

            k_addln<<<MROWS, 256, 0, stream>>>(hxB, x16,
                                               g2 + i * HID, b2l + i * HID);
        }

        // out-proj with fused permute: nx=2, ny=96 -> 192 blocks
        g_bf16<0,0,1,0,1,512><<<192, 512, 0, stream>>>(
            x16, woutT, bout, out, nullptr, nullptr, NPIX, 2);

    } else {
        // ===== FALLBACK: round-10 proven path (fp32 residual) =====
        float* x32 = (float*)d_ws;
        u16*   q16 = (u16*)(x32 + NB);
        u16*   k16 = q16 + NB;
        u16*   v16 = k16 + NB;
        u16*   hid16  = q16;
        float* logits = (float*)q16;

        k_embed_fb<<<MROWS, 256, 0, stream>>>(X, emb, x32);

        dim3 gQKV(HID / 128, MROWS / 128);
        dim3 gW1(FILT / 128, (MROWS / 2) / 128);
        dim3 gW2(HID / 128, (MROWS / 2) / 128);
        dim3 gOut(NPIX / 128, MROWS / 128);

        for (int i = 0; i < L_; ++i) {
            const float* wq = Wq + (size_t)i * HID * HID;
            const float* wk = Wk + (size_t)i * HID * HID;
            const float* wv = Wv + (size_t)i * HID * HID;
            const float* wo = Wo + (size_t)i * HID * HID;

            g_mfma<0,1,0,0><<<gQKV, 256, 0, stream>>>(x32, wq, nullptr, q16, HID, HID);
            g_mfma<0,1,0,0><<<gQKV, 256, 0, stream>>>(x32, wk, nullptr, k16, HID, HID);
            g_mfma<0,1,0,0><<<gQKV, 256, 0, stream>>>(x32, wv, nullptr, v16, HID, HID);

            k_attn<<<dim3(S_ / BLEN, B_ * HEADS), 256, 0, stream>>>(q16, k16, v16, q16);

            g_mfma<1,1,0,0><<<gQKV, 256, 0, stream>>>(q16, wo, nullptr, k16, HID, HID);
            k_addln_fb<<<MROWS, 256, 0, stream>>>(k16, x32,
                                                  g1 + i * HID, b1l + i * HID);

            for (int c = 0; c < 2; ++c) {
                const size_t r0 = (size_t)c * (MROWS / 2);
                g_mfma<0,1,1,1><<<gW1, 256, 0, stream>>>(
                    x32 + r0 * HID, W1 + (size_t)i * HID * FILT,
                    bb1 + i * FILT, hid16, FILT, HID);
                g_mfma<1,1,1,0><<<gW2, 256, 0, stream>>>(
                    hid16, W2 + (size_t)i * FILT * HID,
                    bb2 + i * HID, v16 + r0 * HID, HID, FILT);
            }
            k_addln_fb<<<MROWS, 256, 0, stream>>>(v16, x32,
                                                  g2 + i * HID, b2l + i * HID);
        }

        g_mfma<0,0,1,0><<<gOut, 256, 0, stream>>>(x32, Wout, bout, logits, NPIX, HID);
        k_permute<<<MROWS, 256, 0, stream>>>(logits, out);
    }
}

// Round 22
// 1781.664 us; speedup vs baseline: 1.0764x; 1.0672x over previous
//
#include <hip/hip_runtime.h>
#include <hip/hip_bf16.h>
#include <cstdint>

#define B_    8
#define C_    3
#define H_    32
#define W_    32
#define HID   512
#define HEADS 8
#define FILT  2048
#define L_    6
#define BLEN  256
#define NPIX  256
#define S_    (H_*W_*C_)   /* 3072 */
#define MROWS (B_*S_)      /* 24576 */

typedef unsigned short u16;
typedef short bf16x8 __attribute__((ext_vector_type(8)));
typedef float f32x4  __attribute__((ext_vector_type(4)));

__device__ __forceinline__ float bf2f(u16 u) {
    union { unsigned int i; float f; } x; x.i = ((unsigned int)u) << 16; return x.f;
}
__device__ __forceinline__ u16 f2bf(float f) {
    __hip_bfloat16 h = __float2bfloat16(f);
    return *reinterpret_cast<u16*>(&h);
}

#define GLP(p) ((const __attribute__((address_space(1))) void*)(p))
#define LLP(p) ((__attribute__((address_space(3))) void*)(p))

// ---------------------------------------------------------------------------
// Embedding gather + shift + positional -> x16 (bf16 residual stream).
// ---------------------------------------------------------------------------
__global__ __launch_bounds__(256) void k_embed(const float* __restrict__ X,
                                               const float* __restrict__ emb,
                                               u16* __restrict__ xo16) {
    int r = blockIdx.x;              // b*S + s
    int b = r / S_, s = r - b * S_;
    int h = s / (W_ * C_);
    int j = s - h * (W_ * C_);
    int tid = threadIdx.x;
    int d0 = tid << 1;               // 0,2,..,510

    float e0 = 0.f, e1 = 0.f;
    if (s > 0) {
        int sp = s - 1;
        int hp = sp / (W_ * C_);
        int jp = sp - hp * (W_ * C_);
        int cp = jp % C_;
        int wp = jp / C_;
        float xv = X[(((size_t)b * C_ + cp) * H_ + hp) * W_ + wp];
        int iv = (int)(xv * 255.0f) + cp * NPIX;
        float2 ev = *(const float2*)(emb + (size_t)iv * HID + d0);
        e0 = ev.x * 22.627416997969522f;   // sqrt(512)
        e1 = ev.y * 22.627416997969522f;
    }
    float p01[2];
#pragma unroll
    for (int q = 0; q < 2; ++q) {
        int d = d0 + q;
        float invd = expf((float)(d & 127) * -0.07252236513366287f);
        p01[q] = (d < 128) ? sinf((float)h * invd)
               : (d < 256) ? cosf((float)h * invd)
               : (d < 384) ? sinf((float)j * invd)
                           : cosf((float)j * invd);
    }
    ushort2 o;
    o.x = f2bf(e0 + p01[0]);
    o.y = f2bf(e1 + p01[1]);
    *(ushort2*)(xo16 + (size_t)r * HID + d0) = o;
}

// ---------------------------------------------------------------------------
// 64x64 tile transpose+convert: out[N][K] (bf16) = in[K][N] (fp32).
// ---------------------------------------------------------------------------
__global__ __launch_bounds__(256) void k_trans_g(const float* __restrict__ in,
                                                 u16* __restrict__ out,
                                                 int N, int K,
                                                 size_t inStride, size_t outStride) {
    __shared__ u16 T[64][72];
    in  += (size_t)blockIdx.z * inStride;
    out += (size_t)blockIdx.z * outStride;
    int n0 = blockIdx.x * 64, k0 = blockIdx.y * 64;
    int t = threadIdx.x;
    int r4 = t >> 4;            // 0..15
    int c4 = (t & 15) << 2;     // 0..60
#pragma unroll
    for (int pass = 0; pass < 4; ++pass) {
        int kr = pass * 16 + r4;
        float4 v = *(const float4*)(in + (size_t)(k0 + kr) * N + n0 + c4);
        T[c4 + 0][kr] = f2bf(v.x);
        T[c4 + 1][kr] = f2bf(v.y);
        T[c4 + 2][kr] = f2bf(v.z);
        T[c4 + 3][kr] = f2bf(v.w);
    }
    __syncthreads();
#pragma unroll
    for (int pass = 0; pass < 4; ++pass) {
        int n = pass * 16 + r4;
        ushort4 s = {T[n][c4], T[n][c4 + 1], T[n][c4 + 2], T[n][c4 + 3]};
        *(ushort4*)(out + (size_t)(n0 + n) * K + k0 + c4) = s;
    }
}

// ---------------------------------------------------------------------------
// Pure-bf16 MFMA GEMM, 256x128 tile, 8 waves (512 thr), BK=64, single-buffer
// (proven round-19 config).  For LARGE grids (QKV, FFN1).
// ---------------------------------------------------------------------------
template<int QKV, int C_BF, int BIAS, int RELU, int PERM, int KT>
__global__ __launch_bounds__(512) void g_bf16(const u16* __restrict__ A,
                                              const u16* __restrict__ Bt,
                                              const float* __restrict__ bias,
                                              void* __restrict__ C0,
                                              void* __restrict__ C1,
                                              void* __restrict__ C2,
                                              int Nc, int nx) {
    __shared__ __align__(16) u16 smem[24576];   // As 16384 | Bs 8192 (49152 B)
    u16* As = smem;
    u16* Bs = smem + 16384;
    int tid  = threadIdx.x;
    int lane = tid & 63;
    int w    = tid >> 6;                 // 0..7

    int qg  = (int)gridDim.x >> 3;
    int wg  = (blockIdx.x & 7) * qg + (blockIdx.x >> 3);
    int bx  = wg % nx, by = wg / nx;
    int row0 = by * 256, col0 = bx * 128;

    int l8 = lane >> 3;                  // 0..7
    int l7 = lane & 7;                   // 0..7
    int scol = (l7 ^ l8) << 3;           // pre-swizzled source col (elems)
    const u16* aP = A  + (size_t)(row0 + w * 32 + l8) * KT + scol;
    const u16* bP = Bt + (size_t)(col0 + w * 16 + l8) * KT + scol;
    u16* asBase = As + w * 2048;         // 32 rows x 64 per wave
    u16* bsBase = Bs + w * 1024;         // 16 rows x 64 per wave

    int wr = (w >> 1) << 6;              // 0,64,128,192 (M quadrant)
    int wc = (w & 1) << 6;               // 0,64         (N quadrant)
    int lr = lane & 15;
    int kb = lane >> 4;

    f32x4 acc[4][4];
#pragma unroll
    for (int mi = 0; mi < 4; ++mi)
#pragma unroll
        for (int nj = 0; nj < 4; ++nj)
            acc[mi][nj] = (f32x4){0.f, 0.f, 0.f, 0.f};

    for (int k0 = 0; k0 < KT; k0 += 64) {
#pragma unroll
        for (int p = 0; p < 4; ++p)
            __builtin_amdgcn_global_load_lds(GLP(aP + (size_t)p * 8 * KT),
                                             LLP(asBase + p * 512), 16, 0, 0);
#pragma unroll
        for (int p = 0; p < 2; ++p)
            __builtin_amdgcn_global_load_lds(GLP(bP + (size_t)p * 8 * KT),
                                             LLP(bsBase + p * 512), 16, 0, 0);
        aP += 64; bP += 64;
        __syncthreads();

#pragma unroll
        for (int kh = 0; kh < 2; ++kh) {
            int sl = ((kh << 2) + kb) ^ (lr & 7);
            bf16x8 af[4], bv[4];
#pragma unroll
            for (int mi = 0; mi < 4; ++mi)
                af[mi] = *(const bf16x8*)&As[(wr + lr) * 64 + mi * 1024 + sl * 8];
#pragma unroll
            for (int nj = 0; nj < 4; ++nj)
                bv[nj] = *(const bf16x8*)&Bs[(wc + lr) * 64 + nj * 1024 + sl * 8];
            __builtin_amdgcn_s_setprio(1);
#pragma unroll
            for (int mi = 0; mi < 4; ++mi)
#pragma unroll
                for (int nj = 0; nj < 4; ++nj)
                    acc[mi][nj] = __builtin_amdgcn_mfma_f32_16x16x32_bf16(
                        af[mi], bv[nj], acc[mi][nj], 0, 0, 0);
            __builtin_amdgcn_s_setprio(0);
        }
        __syncthreads();
    }

    if (C_BF) {
        u16* Cp; int cbase;
        if (QKV) {
            int sel = col0 >> 9;
            Cp = (u16*)(sel == 0 ? C0 : sel == 1 ? C1 : C2);
            cbase = col0 & 511;
        } else { Cp = (u16*)C0; cbase = col0; }
#pragma unroll
        for (int pass = 0; pass < 2; ++pass) {
            if ((w >> 2) == pass) {              // waves owning rows pass*128..+127
                int rbase = wr - pass * 128;     // 0 or 64
#pragma unroll
                for (int nj = 0; nj < 4; ++nj) {
                    int colL = wc + (nj << 4) + lr;
                    float bsv = BIAS ? bias[col0 + colL] : 0.f;
#pragma unroll
                    for (int mi = 0; mi < 4; ++mi)
#pragma unroll
                        for (int reg = 0; reg < 4; ++reg) {
                            int rowL = rbase + (mi << 4) + (kb << 2) + reg;
                            float v = acc[mi][nj][reg] + bsv;
                            if (RELU) v = fmaxf(v, 0.f);
                            smem[rowL * 136 + colL] = f2bf(v);
                        }
                }
            }
            __syncthreads();
#pragma unroll
            for (int it = 0; it < 4; ++it) {
                int job  = tid + (it << 9);      // 2048 jobs = 128 rows x 16 slots
                int rowL = job >> 4;
                int colL = (job & 15) << 3;
                bf16x8 vv = *(const bf16x8*)&smem[rowL * 136 + colL];
                *(bf16x8*)(Cp + (size_t)(row0 + pass * 128 + rowL) * Nc
                               + cbase + colL) = vv;
            }
            __syncthreads();
        }
    } else {
#pragma unroll
        for (int nj = 0; nj < 4; ++nj) {
            int colg = col0 + wc + (nj << 4) + lr;
            float bsv = BIAS ? bias[colg] : 0.f;
#pragma unroll
            for (int mi = 0; mi < 4; ++mi)
#pragma unroll
                for (int reg = 0; reg < 4; ++reg) {
                    int row = row0 + wr + (mi << 4) + (kb << 2) + reg;
                    float v = acc[mi][nj][reg] + bsv;
                    if (RELU) v = fmaxf(v, 0.f);
                    if (PERM) {
                        int bb = row / S_;
                        int ss = row - bb * S_;
                        int hh = ss / (W_ * C_);
                        int jj = ss - hh * (W_ * C_);
                        int ww = jj / C_;
                        int cc = jj - ww * C_;
                        ((float*)C0)[((((size_t)bb * C_ + cc) * H_ + hh) * W_ + ww)
                                     * NPIX + colg] = v;
                    } else {
                        ((float*)C0)[(size_t)row * Nc + colg] = v;
                    }
                }
        }
    }
}

// ---------------------------------------------------------------------------
// Pure-bf16 MFMA GEMM, 128x128 tile, 4 waves (256 thr), BK=64 (proven
// round-17 config; 34.8KB LDS -> 4 blocks/CU).  For SMALL grids (N<=512
// dispatches: O-proj, FFN2, out-proj) where the 256x128 kernel leaves a
// half-empty residency wave (dispatch tail).
// ---------------------------------------------------------------------------
template<int QKV, int C_BF, int BIAS, int RELU, int PERM, int KT>
__global__ __launch_bounds__(256) void g_sm(const u16* __restrict__ A,
                                            const u16* __restrict__ Bt,
                                            const float* __restrict__ bias,
                                            void* __restrict__ C0,
                                            void* __restrict__ C1,
                                            void* __restrict__ C2,
                                            int Nc, int nx) {
    __shared__ __align__(16) u16 smem[17408];
    u16* As = smem;
    u16* Bs = smem + 8192;
    int tid  = threadIdx.x;
    int lane = tid & 63;
    int w    = tid >> 6;

    int qg  = (int)gridDim.x >> 3;
    int wg  = (blockIdx.x & 7) * qg + (blockIdx.x >> 3);
    int bx  = wg % nx, by = wg / nx;
    int row0 = by * 128, col0 = bx * 128;

    int l8 = lane >> 3;                   // 0..7
    int l7 = lane & 7;                    // 0..7
    int scol = (l7 ^ l8) << 3;            // pre-swizzled source col (elems)
    const u16* aP = A  + (size_t)(row0 + w * 32 + l8) * KT + scol;
    const u16* bP = Bt + (size_t)(col0 + w * 32 + l8) * KT + scol;
    u16* asBase = As + w * 2048;
    u16* bsBase = Bs + w * 2048;

    int wr = (w >> 1) << 6;
    int wc = (w & 1) << 6;
    int lr = lane & 15;
    int kb = lane >> 4;

    f32x4 acc[4][4];
#pragma unroll
    for (int mi = 0; mi < 4; ++mi)
#pragma unroll
        for (int nj = 0; nj < 4; ++nj)
            acc[mi][nj] = (f32x4){0.f, 0.f, 0.f, 0.f};

    for (int k0 = 0; k0 < KT; k0 += 64) {
#pragma unroll
        for (int p = 0; p < 4; ++p) {
            __builtin_amdgcn_global_load_lds(GLP(aP + (size_t)p * 8 * KT),
                                             LLP(asBase + p * 512), 16, 0, 0);
            __builtin_amdgcn_global_load_lds(GLP(bP + (size_t)p * 8 * KT),
                                             LLP(bsBase + p * 512), 16, 0, 0);
        }
        aP += 64; bP += 64;
        __syncthreads();

#pragma unroll
        for (int kh = 0; kh < 2; ++kh) {
            int sl = ((kh << 2) + kb) ^ (lr & 7);
            bf16x8 af[4], bv[4];
#pragma unroll
            for (int mi = 0; mi < 4; ++mi)
                af[mi] = *(const bf16x8*)&As[(wr + lr) * 64 + mi * 1024 + sl * 8];
#pragma unroll
            for (int nj = 0; nj < 4; ++nj)
                bv[nj] = *(const bf16x8*)&Bs[(wc + lr) * 64 + nj * 1024 + sl * 8];
            __builtin_amdgcn_s_setprio(1);
#pragma unroll
            for (int mi = 0; mi < 4; ++mi)
#pragma unroll
                for (int nj = 0; nj < 4; ++nj)
                    acc[mi][nj] = __builtin_amdgcn_mfma_f32_16x16x32_bf16(
                        af[mi], bv[nj], acc[mi][nj], 0, 0, 0);
            __builtin_amdgcn_s_setprio(0);
        }
        __syncthreads();
    }

    if (C_BF) {
#pragma unroll
        for (int nj = 0; nj < 4; ++nj) {
            int colL = wc + (nj << 4) + lr;
            float bsv = BIAS ? bias[col0 + colL] : 0.f;
#pragma unroll
            for (int mi = 0; mi < 4; ++mi)
#pragma unroll
                for (int reg = 0; reg < 4; ++reg) {
                    int rowL = wr + (mi << 4) + (kb << 2) + reg;
                    float v = acc[mi][nj][reg] + bsv;
                    if (RELU) v = fmaxf(v, 0.f);
                    smem[rowL * 136 + colL] = f2bf(v);
                }
        }
        __syncthreads();
        u16* Cp; int cbase;
        if (QKV) {
            int sel = col0 >> 9;
            Cp = (u16*)(sel == 0 ? C0 : sel == 1 ? C1 : C2);
            cbase = col0 & 511;
        } else { Cp = (u16*)C0; cbase = col0; }
#pragma unroll
        for (int it = 0; it < 8; ++it) {
            int job  = tid + (it << 8);
            int rowL = job >> 4;
            int colL = (job & 15) << 3;
            bf16x8 vv = *(const bf16x8*)&smem[rowL * 136 + colL];
            *(bf16x8*)(Cp + (size_t)(row0 + rowL) * Nc + cbase + colL) = vv;
        }
    } else {
#pragma unroll
        for (int nj = 0; nj < 4; ++nj) {
            int colg = col0 + wc + (nj << 4) + lr;
            float bsv = BIAS ? bias[colg] : 0.f;
#pragma unroll
            for (int mi = 0; mi < 4; ++mi)
#pragma unroll
                for (int reg = 0; reg < 4; ++reg) {
                    int row = row0 + wr + (mi << 4) + (kb << 2) + reg;
                    float v = acc[mi][nj][reg] + bsv;
                    if (RELU) v = fmaxf(v, 0.f);
                    if (PERM) {
                        int bb = row / S_;
                        int ss = row - bb * S_;
                        int hh = ss / (W_ * C_);
                        int jj = ss - hh * (W_ * C_);
                        int ww = jj / C_;
                        int cc = jj - ww * C_;
                        ((float*)C0)[((((size_t)bb * C_ + cc) * H_ + hh) * W_ + ww)
                                     * NPIX + colg] = v;
                    } else {
                        ((float*)C0)[(size_t)row * Nc + colg] = v;
                    }
                }
        }
    }
}

// ---------------------------------------------------------------------------
// LEGACY fp32-staged MFMA GEMM — fallback path only.
// ---------------------------------------------------------------------------
template<int A_BF, int C_BF, int BIAS, int RELU>
__global__ __launch_bounds__(256) void g_mfma(const void* __restrict__ Ap,
                                              const float* __restrict__ Bw,
                                              const float* __restrict__ bias,
                                              void* __restrict__ Cp,
                                              int N, int K) {
    __shared__ __align__(16) u16 As[128][40];
    __shared__ __align__(16) u16 Bs[128][40];
    int tid  = threadIdx.x;
    int row0 = blockIdx.y * 128, col0 = blockIdx.x * 128;

    int ar  = tid >> 1;
    int akq = (tid & 1) << 4;
    int bkk = tid >> 5;
    int bnn = (tid & 31) << 2;

    int lane = tid & 63;
    int wv   = tid >> 6;
    int wr   = (wv >> 1) << 6;
    int wc   = (wv & 1) << 6;
    int lr   = lane & 15;
    int kb   = lane >> 4;

    f32x4 acc[4][4];
#pragma unroll
    for (int mi = 0; mi < 4; ++mi)
#pragma unroll
        for (int nj = 0; nj < 4; ++nj)
            acc[mi][nj] = (f32x4){0.f, 0.f, 0.f, 0.f};

    for (int k0 = 0; k0 < K; k0 += 32) {
        if (A_BF) {
            const u16* ap = (const u16*)Ap + (size_t)(row0 + ar) * K + k0 + akq;
#pragma unroll
            for (int p = 0; p < 4; ++p)
                *(ushort4*)&As[ar][akq + (p << 2)] = *(const ushort4*)(ap + (p << 2));
        } else {
            const float* ap = (const float*)Ap + (size_t)(row0 + ar) * K + k0 + akq;
#pragma unroll
            for (int p = 0; p < 4; ++p) {
                float4 v = *(const float4*)(ap + (p << 2));
                ushort4 wq = {f2bf(v.x), f2bf(v.y), f2bf(v.z), f2bf(v.w)};
                *(ushort4*)&As[ar][akq + (p << 2)] = wq;
            }
        }
#pragma unroll
        for (int p = 0; p < 4; ++p) {
            int kl = bkk + (p << 3);
            float4 wv4 = *(const float4*)(Bw + (size_t)(k0 + kl) * N + col0 + bnn);
            Bs[bnn + 0][kl] = f2bf(wv4.x);
            Bs[bnn + 1][kl] = f2bf(wv4.y);
            Bs[bnn + 2][kl] = f2bf(wv4.z);
            Bs[bnn + 3][kl] = f2bf(wv4.w);
        }
        __syncthreads();

        bf16x8 af[4], bfr[4];
#pragma unroll
        for (int mi = 0; mi < 4; ++mi)
            af[mi] = *(const bf16x8*)&As[wr + (mi << 4) + lr][kb << 3];
#pragma unroll
        for (int nj = 0; nj < 4; ++nj)
            bfr[nj] = *(const bf16x8*)&Bs[wc + (nj << 4) + lr][kb << 3];
#pragma unroll
        for (int mi = 0; mi < 4; ++mi)
#pragma unroll
            for (int nj = 0; nj < 4; ++nj)
                acc[mi][nj] = __builtin_amdgcn_mfma_f32_16x16x32_bf16(
                    af[mi], bfr[nj], acc[mi][nj], 0, 0, 0);
        __syncthreads();
    }

#pragma unroll
    for (int mi = 0; mi < 4; ++mi)
#pragma unroll
        for (int nj = 0; nj < 4; ++nj) {
            int col = col0 + wc + (nj << 4) + lr;
            float bsv = BIAS ? bias[col] : 0.f;
#pragma unroll
            for (int reg = 0; reg < 4; ++reg) {
                int row = row0 + wr + (mi << 4) + (kb << 2) + reg;
                float v = acc[mi][nj][reg] + bsv;
                if (RELU) v = fmaxf(v, 0.f);
                if (C_BF)
                    ((u16*)Cp)[(size_t)row * N + col] = f2bf(v);
                else
                    ((float*)Cp)[(size_t)row * N + col] = v;
            }
        }
}

// ---------------------------------------------------------------------------
// MFMA flash-style block-local causal attention (bf16), SWAPPED QK^T,
// XCD-aware 1D grid + K/V register prefetch.  Diag/non-diag softmax split:
// the causal-mask compare only runs on chunks crossing the diagonal
// (~1.6 of 8); wave-uniform branch.
// ---------------------------------------------------------------------------
__global__ __launch_bounds__(256) void k_attn_mfma(const u16* Qm,
                                                   const u16* __restrict__ Km,
                                                   const u16* __restrict__ Vm,
                                                   u16* Om) {
    __shared__ __align__(16) u16 Kl[64][72];      // [key][d]
    __shared__ __align__(16) u16 VT[64][72];      // [d][key^vsw]
    __shared__ __align__(16) u16 Pl[4][64][64];   // per-wave [q][k^((q&7)<<3)]

    int f   = blockIdx.x;            // 0..767
    int xcd = f & 7;
    int t2  = f >> 3;
    int qb  = t2 % 12;
    int grp = t2 / 12;               // 0..7
    int bh  = (grp << 3) | xcd;
    int b   = bh >> 3, h = bh & 7;

    int tid = threadIdx.x;
    int lane = tid & 63;
    int w    = tid >> 6;
    int lr   = lane & 15;
    int kb   = lane >> 4;            // 0..3
    int qw   = qb * BLEN + w * 64;   // wave query base
    int vsw  = (tid & 7) << 3;       // VT write swizzle
    int psw  = (lr & 7) << 3;        // Pl swizzle for this lane's rows (q&7)

    bf16x8 qf[4][2];
#pragma unroll
    for (int mi = 0; mi < 4; ++mi)
#pragma unroll
        for (int ks = 0; ks < 2; ++ks)
            qf[mi][ks] = *(const bf16x8*)(Qm +
                ((size_t)b * S_ + qw + mi * 16 + lr) * HID + h * 64 + ks * 32 + kb * 8);

    f32x4 oacc[4][4];                 // [mi][dj]
    float lacc[4];
#pragma unroll
    for (int mi = 0; mi < 4; ++mi) {
        lacc[mi] = 0.f;
#pragma unroll
        for (int dj = 0; dj < 4; ++dj)
            oacc[mi][dj] = (f32x4){0.f, 0.f, 0.f, 0.f};
    }

    int kstart = (qb == 0) ? 0 : (qb - 1) * BLEN;
    int nch    = (qb == 0) ? 4 : 8;

    int key0 = tid >> 3;
    int key1 = (tid + 256) >> 3;
    int d8   = (tid & 7) << 3;

    bf16x8 kvr0, kvr1, vvr0, vvr1;
    {
        size_t g0 = ((size_t)b * S_ + kstart + key0) * HID + h * 64 + d8;
        size_t g1 = ((size_t)b * S_ + kstart + key1) * HID + h * 64 + d8;
        kvr0 = *(const bf16x8*)(Km + g0);
        vvr0 = *(const bf16x8*)(Vm + g0);
        kvr1 = *(const bf16x8*)(Km + g1);
        vvr1 = *(const bf16x8*)(Vm + g1);
    }

    for (int ck = 0; ck < nch; ++ck) {
        int ka = kstart + ck * 64;
        __syncthreads();
        *(bf16x8*)&Kl[key0][d8] = kvr0;
        *(bf16x8*)&Kl[key1][d8] = kvr1;
        {
            const u16* vu0 = (const u16*)&vvr0;
            const u16* vu1 = (const u16*)&vvr1;
            int kc0 = key0 ^ vsw, kc1 = key1 ^ vsw;
#pragma unroll
            for (int e = 0; e < 8; ++e) VT[d8 + e][kc0] = vu0[e];
#pragma unroll
            for (int e = 0; e < 8; ++e) VT[d8 + e][kc1] = vu1[e];
        }
        __syncthreads();

        if (ck + 1 < nch) {
            int kan = ka + 64;
            size_t g0 = ((size_t)b * S_ + kan + key0) * HID + h * 64 + d8;
            size_t g1 = ((size_t)b * S_ + kan + key1) * HID + h * 64 + d8;
            kvr0 = *(const bf16x8*)(Km + g0);
            vvr0 = *(const bf16x8*)(Vm + g0);
            kvr1 = *(const bf16x8*)(Km + g1);
            vvr1 = *(const bf16x8*)(Vm + g1);
        }

        if (ka <= qw + 63) {
            f32x4 sa[4][4];
#pragma unroll
            for (int nj = 0; nj < 4; ++nj)
#pragma unroll
                for (int mi = 0; mi < 4; ++mi)
                    sa[nj][mi] = (f32x4){0.f, 0.f, 0.f, 0.f};
#pragma unroll
            for (int ks = 0; ks < 2; ++ks) {
                bf16x8 kf[4];
#pragma unroll
                for (int nj = 0; nj < 4; ++nj)
                    kf[nj] = *(const bf16x8*)&Kl[nj * 16 + lr][ks * 32 + kb * 8];
                __builtin_amdgcn_s_setprio(1);
#pragma unroll
                for (int nj = 0; nj < 4; ++nj)
#pragma unroll
                    for (int mi = 0; mi < 4; ++mi)
                        sa[nj][mi] = __builtin_amdgcn_mfma_f32_16x16x32_bf16(
                            kf[nj], qf[mi][ks], sa[nj][mi], 0, 0, 0);
                __builtin_amdgcn_s_setprio(0);
            }
            if (ka + 63 > qw) {
                // ---- diagonal chunk: masked softmax ----
#pragma unroll
                for (int mi = 0; mi < 4; ++mi) {
                    int qg2 = qw + mi * 16 + lr;
                    float tsum = 0.f;
#pragma unroll
                    for (int nj = 0; nj < 4; ++nj) {
                        ushort4 pk;
                        u16* pp = (u16*)&pk;
#pragma unroll
                        for (int reg = 0; reg < 4; ++reg) {
                            float s = sa[nj][mi][reg] * 0.125f;
                            float p = __expf(s);
                            if (ka + nj * 16 + kb * 4 + reg > qg2) p = 0.f;
                            tsum += p;
                            pp[reg] = f2bf(p);
                        }
                        *(ushort4*)&Pl[w][mi * 16 + lr][(nj * 16 + kb * 4) ^ psw] = pk;
                    }
                    tsum += __shfl_xor(tsum, 16);
                    tsum += __shfl_xor(tsum, 32);
                    lacc[mi] += tsum;
                }
            } else {
                // ---- interior chunk: no mask ----
#pragma unroll
                for (int mi = 0; mi < 4; ++mi) {
                    float tsum = 0.f;
#pragma unroll
                    for (int nj = 0; nj < 4; ++nj) {
                        ushort4 pk;
                        u16* pp = (u16*)&pk;
#pragma unroll
                        for (int reg = 0; reg < 4; ++reg) {
                            float s = sa[nj][mi][reg] * 0.125f;
                            float p = __expf(s);
                            tsum += p;
                            pp[reg] = f2bf(p);
                        }
                        *(ushort4*)&Pl[w][mi * 16 + lr][(nj * 16 + kb * 4) ^ psw] = pk;
                    }
                    tsum += __shfl_xor(tsum, 16);
                    tsum += __shfl_xor(tsum, 32);
                    lacc[mi] += tsum;
                }
            }
#pragma unroll
            for (int ks = 0; ks < 2; ++ks) {
                bf16x8 pf[4], vf[4];
#pragma unroll
                for (int mi = 0; mi < 4; ++mi)
                    pf[mi] = *(const bf16x8*)&Pl[w][mi * 16 + lr]
                                                 [(ks * 32 + kb * 8) ^ psw];
#pragma unroll
                for (int dj = 0; dj < 4; ++dj) {
                    int vr = ((dj * 2 + (lr >> 3)) & 7) << 3;
                    vf[dj] = *(const bf16x8*)&VT[dj * 16 + lr]
                                                [(ks * 32 + kb * 8) ^ vr];
                }
                __builtin_amdgcn_s_setprio(1);
#pragma unroll
                for (int mi = 0; mi < 4; ++mi)
#pragma unroll
                    for (int dj = 0; dj < 4; ++dj)
                        oacc[mi][dj] = __builtin_amdgcn_mfma_f32_16x16x32_bf16(
                            pf[mi], vf[dj], oacc[mi][dj], 0, 0, 0);
                __builtin_amdgcn_s_setprio(0);
            }
        }
    }

#pragma unroll
    for (int mi = 0; mi < 4; ++mi) {
        float lr4[4];
#pragma unroll
        for (int reg = 0; reg < 4; ++reg)
            lr4[reg] = __shfl(lacc[mi], kb * 4 + reg);
#pragma unroll
        for (int reg = 0; reg < 4; ++reg) {
            float rl = 1.0f / lr4[reg];
            size_t orow = ((size_t)b * S_ + qw + mi * 16 + kb * 4 + reg) * HID + h * 64;
#pragma unroll
            for (int dj = 0; dj < 4; ++dj)
                Om[orow + dj * 16 + lr] = f2bf(oacc[mi][dj][reg] * rl);
        }
    }
}

// ---------------------------------------------------------------------------
// LEGACY scalar attention — fallback path only.
// ---------------------------------------------------------------------------
__global__ __launch_bounds__(256) void k_attn(const u16* Qm,
                                              const u16* __restrict__ Km,
                                              const u16* __restrict__ Vm,
                                              u16* Om) {
    __shared__ float Ks[64][64];
    __shared__ float Vs[64][64];
    int qb  = blockIdx.x;
    int bh  = blockIdx.y;
    int b   = bh >> 3, h = bh & 7;
    int tid = threadIdx.x;
    int sq  = qb * BLEN + tid;

    size_t qoff = ((size_t)b * S_ + sq) * HID + h * 64;
    float q[64];
#pragma unroll
    for (int d = 0; d < 64; d += 4) {
        ushort4 u = *(const ushort4*)(Qm + qoff + d);
        q[d]   = bf2f(u.x) * 0.125f;
        q[d+1] = bf2f(u.y) * 0.125f;
        q[d+2] = bf2f(u.z) * 0.125f;
        q[d+3] = bf2f(u.w) * 0.125f;
    }

    float acc[64];
#pragma unroll
    for (int d = 0; d < 64; ++d) acc[d] = 0.f;
    float l = 0.f;

    int kstart  = (qb == 0) ? 0 : (qb - 1) * BLEN;
    int nchunks = (qb == 0) ? 4 : 8;

    for (int ck = 0; ck < nchunks; ++ck) {
        int ka = kstart + ck * 64;
        __syncthreads();
        int li = tid;
#pragma unroll
        for (int it = 0; it < 4; ++it, li += 256) {
            int key = li >> 4;
            int seg = (li & 15) * 4;
            size_t goff = ((size_t)b * S_ + ka + key) * HID + h * 64 + seg;
            ushort4 ku = *(const ushort4*)(Km + goff);
            ushort4 vu = *(const ushort4*)(Vm + goff);
            Ks[key][seg+0] = bf2f(ku.x); Ks[key][seg+1] = bf2f(ku.y);
            Ks[key][seg+2] = bf2f(ku.z); Ks[key][seg+3] = bf2f(ku.w);
            Vs[key][seg+0] = bf2f(vu.x); Vs[key][seg+1] = bf2f(vu.y);
            Vs[key][seg+2] = bf2f(vu.z); Vs[key][seg+3] = bf2f(vu.w);
        }
        __syncthreads();

        int nk = sq - ka + 1;
        if (nk > 64) nk = 64;
        for (int kk = 0; kk < nk; ++kk) {
            float dot = 0.f;
#pragma unroll
            for (int d = 0; d < 64; ++d) dot += q[d] * Ks[kk][d];
            float p = expf(dot);
            l += p;
#pragma unroll
            for (int d = 0; d < 64; ++d) acc[d] += p * Vs[kk][d];
        }
    }

    float rl = 1.0f / l;
    size_t ooff = ((size_t)b * S_ + sq) * HID + h * 64;
#pragma unroll
    for (int d = 0; d < 64; d += 4) {
        ushort4 s;
        s.x = f2bf(acc[d]   * rl); s.y = f2bf(acc[d+1] * rl);
        s.z = f2bf(acc[d+2] * rl); s.w = f2bf(acc[d+3] * rl);
        *(ushort4*)(Om + ooff + d) = s;
    }
}

// ---------------------------------------------------------------------------
// X16 = LayerNorm(T16 + X16) * g + b   (bf16 residual stream, fp32 math)
// ---------------------------------------------------------------------------
__global__ __launch_bounds__(256) void k_addln(const u16* __restrict__ T,
                                               u16* __restrict__ X16,
                                               const float* __restrict__ g,
                                               const float* __restrict__ bb) {
    __shared__ float red[8];
    int r = blockIdx.x;
    size_t off = (size_t)r * HID;
    int tid = threadIdx.x;
    int c0 = tid << 1;
    ushort2 tv = *(const ushort2*)(T + off + c0);
    ushort2 xv = *(const ushort2*)(X16 + off + c0);
    float v0 = bf2f(tv.x) + bf2f(xv.x);
    float v1 = bf2f(tv.y) + bf2f(xv.y);
    float s  = v0 + v1;
    float sq = v0 * v0 + v1 * v1;
#pragma unroll
    for (int o = 32; o > 0; o >>= 1) {
        s  += __shfl_down(s,  o, 64);
        sq += __shfl_down(sq, o, 64);
    }
    int wid = tid >> 6;
    if ((tid & 63) == 0) { red[wid] = s; red[4 + wid] = sq; }
    __syncthreads();
    if (tid == 0) {
        red[0] = red[0] + red[1] + red[2] + red[3];
        red[4] = red[4] + red[5] + red[6] + red[7];
    }
    __syncthreads();
    float mean = red[0] * (1.0f / 512.0f);
    float var  = red[4] * (1.0f / 512.0f) - mean * mean;
    float rs   = rsqrtf(var + 1e-6f);
    float2 gv = *(const float2*)(g + c0);
    float2 bv = *(const float2*)(bb + c0);
    ushort2 o;
    o.x = f2bf((v0 - mean) * rs * gv.x + bv.x);
    o.y = f2bf((v1 - mean) * rs * gv.y + bv.y);
    *(ushort2*)(X16 + off + c0) = o;
}

// ---------------------------------------------------------------------------
// Fallback-path add+LN (fp32 residual) — round-10 logic.
// ---------------------------------------------------------------------------
__global__ __launch_bounds__(256) void k_addln_fb(const u16* __restrict__ T,
                                                  float* __restrict__ X,
                                                  const float* __restrict__ g,
                                                  const float* __restrict__ bb) {
    __shared__ float red[8];
    int r = blockIdx.x;
    size_t off = (size_t)r * HID;
    int tid = threadIdx.x;
    float v0 = bf2f(T[off + tid])       + X[off + tid];
    float v1 = bf2f(T[off + tid + 256]) + X[off + tid + 256];
    float s  = v0 + v1;
    float sq = v0 * v0 + v1 * v1;
#pragma unroll
    for (int o = 32; o > 0; o >>= 1) {
        s  += __shfl_down(s,  o, 64);
        sq += __shfl_down(sq, o, 64);
    }
    int wid = tid >> 6;
    if ((tid & 63) == 0) { red[wid] = s; red[4 + wid] = sq; }
    __syncthreads();
    if (tid == 0) {
        red[0] = red[0] + red[1] + red[2] + red[3];
        red[4] = red[4] + red[5] + red[6] + red[7];
    }
    __syncthreads();
    float mean = red[0] * (1.0f / 512.0f);
    float var  = red[4] * (1.0f / 512.0f) - mean * mean;
    float rs   = rsqrtf(var + 1e-6f);
    X[off + tid]       = (v0 - mean) * rs * g[tid]       + bb[tid];
    X[off + tid + 256] = (v1 - mean) * rs * g[tid + 256] + bb[tid + 256];
}

// ---------------------------------------------------------------------------
// Fallback embed (fp32 out) — round-10 logic.
// ---------------------------------------------------------------------------
__global__ __launch_bounds__(256) void k_embed_fb(const float* __restrict__ X,
                                                  const float* __restrict__ emb,
                                                  float* __restrict__ xo) {
    int r = blockIdx.x;
    int b = r / S_, s = r - b * S_;
    int h = s / (W_ * C_);
    int j = s - h * (W_ * C_);
    int tid = threadIdx.x;

    float e0 = 0.f, e1 = 0.f;
    if (s > 0) {
        int sp = s - 1;
        int hp = sp / (W_ * C_);
        int jp = sp - hp * (W_ * C_);
        int cp = jp % C_;
        int wp = jp / C_;
        float xv = X[(((size_t)b * C_ + cp) * H_ + hp) * W_ + wp];
        int iv = (int)(xv * 255.0f) + cp * NPIX;
        const float* er = emb + (size_t)iv * HID;
        e0 = er[tid]       * 22.627416997969522f;
        e1 = er[tid + 256] * 22.627416997969522f;
    }
    float invd = expf((float)(tid & 127) * -0.07252236513366287f);
    float p0 = (tid < 128) ? sinf((float)h * invd) : cosf((float)h * invd);
    float p1 = (tid < 128) ? sinf((float)j * invd) : cosf((float)j * invd);

    xo[(size_t)r * HID + tid]       = e0 + p0;
    xo[(size_t)r * HID + tid + 256] = e1 + p1;
}

// ---------------------------------------------------------------------------
// (B,S,NPIX) fp32 logits -> (B,C,H,W,NPIX) fp32 output (fallback only)
// ---------------------------------------------------------------------------
__global__ __launch_bounds__(256) void k_permute(const float* __restrict__ T,
                                                 float* __restrict__ O) {
    int r = blockIdx.x;
    int p = threadIdx.x;
    int b = r / S_, s = r - b * S_;
    int h = s / (W_ * C_);
    int j = s - h * (W_ * C_);
    int w = j / C_;
    int c = j - w * C_;
    O[((((size_t)b * C_ + c) * H_ + h) * W_ + w) * NPIX + p] =
        T[(size_t)r * NPIX + p];
}

// ---------------------------------------------------------------------------
extern "C" void kernel_launch(void* const* d_in, const int* in_sizes, int n_in,
                              void* d_out, int out_size, void* d_ws, size_t ws_size,
                              hipStream_t stream) {
    const float* X    = (const float*)d_in[0];
    const float* emb  = (const float*)d_in[1];
    const float* Wq   = (const float*)d_in[2];
    const float* Wk   = (const float*)d_in[3];
    const float* Wv   = (const float*)d_in[4];
    const float* Wo   = (const float*)d_in[5];
    const float* g1   = (const float*)d_in[6];
    const float* b1l  = (const float*)d_in[7];
    const float* W1   = (const float*)d_in[8];
    const float* bb1  = (const float*)d_in[9];
    const float* W2   = (const float*)d_in[10];
    const float* bb2  = (const float*)d_in[11];
    const float* g2   = (const float*)d_in[12];
    const float* b2l  = (const float*)d_in[13];
    const float* Wout = (const float*)d_in[14];
    const float* bout = (const float*)d_in[15];
    float* out = (float*)d_out;
    (void)in_sizes; (void)n_in; (void)out_size;

    const size_t NB = (size_t)MROWS * HID;
    const size_t BIG_NEED = 189005824ull;   // proven fault-free footprint

    if (ws_size >= BIG_NEED) {
        // ===== BIG PATH (bf16 residual stream) =====
        u16* x16    = (u16*)d_ws;
        u16* q16    = x16 + NB;
        u16* k16    = q16 + NB;
        u16* v16    = k16 + NB;
        u16* hxA    = v16 + NB;            // hidden tail (q16..hxA = 4*NB)
        u16* hxB    = hxA + NB;            // FFN2 output (disjoint from hidden)
        u16* wqkvT  = hxB + NB;
        u16* woT    = wqkvT + (size_t)6 * 1536 * 512;
        u16* w1T    = woT   + (size_t)6 * 512 * 512;
        u16* w2T    = w1T   + (size_t)6 * 2048 * 512;
        u16* woutT  = w2T   + (size_t)6 * 512 * 2048;
        u16* h16    = q16;                 // full FFN hidden = q16..hxA span

        k_trans_g<<<dim3(8, 8, 6),  256, 0, stream>>>(Wq, wqkvT,          512, 512,  262144, 786432);
        k_trans_g<<<dim3(8, 8, 6),  256, 0, stream>>>(Wk, wqkvT + 262144, 512, 512,  262144, 786432);
        k_trans_g<<<dim3(8, 8, 6),  256, 0, stream>>>(Wv, wqkvT + 524288, 512, 512,  262144, 786432);
        k_trans_g<<<dim3(8, 8, 6),  256, 0, stream>>>(Wo, woT,            512, 512,  262144, 262144);
        k_trans_g<<<dim3(32, 8, 6), 256, 0, stream>>>(W1, w1T,  2048, 512, 1048576, 1048576);
        k_trans_g<<<dim3(8, 32, 6), 256, 0, stream>>>(W2, w2T,  512, 2048, 1048576, 1048576);
        k_trans_g<<<dim3(4, 8, 1),  256, 0, stream>>>(Wout, woutT, 256, 512, 131072, 131072);

        k_embed<<<MROWS, 256, 0, stream>>>(X, emb, x16);

        for (int i = 0; i < L_; ++i) {
            // QKV: 256x128 kernel, nx=12, ny=96 -> 1152 blocks x 512 thr
            g_bf16<1,1,0,0,0,512><<<1152, 512, 0, stream>>>(
                x16, wqkvT + (size_t)i * 1536 * 512, nullptr,
                q16, k16, v16, HID, 12);

            k_attn_mfma<<<768, 256, 0, stream>>>(q16, k16, v16, q16);

            // O-proj: 128x128 kernel, nx=4, ny=192 -> 768 blocks (tail-free)
            g_sm<0,1,0,0,0,512><<<768, 256, 0, stream>>>(
                q16, woT + (size_t)i * 512 * 512, nullptr,
                k16, nullptr, nullptr, HID, 4);
            k_addln<<<MROWS, 256, 0, stream>>>(k16, x16,
                                               g1 + i * HID, b1l + i * HID);

            // FFN1 (merged M=24576): 256x128 kernel, nx=16, ny=96 -> 1536 blocks
            g_bf16<0,1,1,1,0,512><<<1536, 512, 0, stream>>>(
                x16, w1T + (size_t)i * 2048 * 512,
                bb1 + i * FILT, h16, nullptr, nullptr, FILT, 16);
            // FFN2 (merged, K=2048): 128x128 kernel, nx=4, ny=192 -> 768 blocks
            g_sm<0,1,1,0,0,2048><<<768, 256, 0, stream>>>(
                h16, w2T + (size_t)i * 512 * 2048,
                bb2 + i * HID, hxB, nullptr, nullptr, HID, 4);

            k_addln<<<MROWS, 256, 0, stream>>>(hxB, x16,
                                               g2 + i * HID, b2l + i * HID);
        }

        // out-proj with fused permute: 128x128 kernel, nx=2 -> 384 blocks
        g_sm<0,0,1,0,1,512><<<384, 256, 0, stream>>>(
            x16, woutT, bout, out, nullptr, nullptr, NPIX, 2);

    } else {
        // ===== FALLBACK: round-10 proven path (fp32 residual) =====
        float* x32 = (float*)d_ws;
        u16*   q16 = (u16*)(x32 + NB);
        u16*   k16 = q16 + NB;
        u16*   v16 = k16 + NB;
        u16*   hid16  = q16;
        float* logits = (float*)q16;

        k_embed_fb<<<MROWS, 256, 0, stream>>>(X, emb, x32);

        dim3 gQKV(HID / 128, MROWS / 128);
        dim3 gW1(FILT / 128, (MROWS / 2) / 128);
        dim3 gW2(HID / 128, (MROWS / 2) / 128);
        dim3 gOut(NPIX / 128, MROWS / 128);

        for (int i = 0; i < L_; ++i) {
            const float* wq = Wq + (size_t)i * HID * HID;
            const float* wk = Wk + (size_t)i * HID * HID;
            const float* wv = Wv + (size_t)i * HID * HID;
            const float* wo = Wo + (size_t)i * HID * HID;

            g_mfma<0,1,0,0><<<gQKV, 256, 0, stream>>>(x32, wq, nullptr, q16, HID, HID);
            g_mfma<0,1,0,0><<<gQKV, 256, 0, stream>>>(x32, wk, nullptr, k16, HID, HID);
            g_mfma<0,1,0,0><<<gQKV, 256, 0, stream>>>(x32, wv, nullptr, v16, HID, HID);

            k_attn<<<dim3(S_ / BLEN, B_ * HEADS), 256, 0, stream>>>(q16, k16, v16, q16);

            g_mfma<1,1,0,0><<<gQKV, 256, 0, stream>>>(q16, wo, nullptr, k16, HID, HID);
            k_addln_fb<<<MROWS, 256, 0, stream>>>(k16, x32,
                                                  g1 + i * HID, b1l + i * HID);

            for (int c = 0; c < 2; ++c) {
                const size_t r0 = (size_t)c * (MROWS / 2);
                g_mfma<0,1,1,1><<<gW1, 256, 0, stream>>>(
                    x32 + r0 * HID, W1 + (size_t)i * HID * FILT,
                    bb1 + i * FILT, hid16, FILT, HID);
                g_mfma<1,1,1,0><<<gW2, 256, 0, stream>>>(
                    hid16, W2 + (size_t)i * FILT * HID,
                    bb2 + i * HID, v16 + r0 * HID, HID, FILT);
            }
            k_addln_fb<<<MROWS, 256, 0, stream>>>(v16, x32,
                                                  g2 + i * HID, b2l + i * HID);
        }

        g_mfma<0,0,1,0><<<gOut, 256, 0, stream>>>(x32, Wout, bout, logits, NPIX, HID);
        k_permute<<<MROWS, 256, 0, stream>>>(logits, out);
    }
}